// Round 1
// baseline (7336.617 us; speedup 1.0000x reference)
//
#include <hip/hip_runtime.h>
#include <math.h>

#define BB 2
#define CDIM 256
#define NQ 4096   // 16*16*16
#define NK 2048   // 8*16*16
#define BH 16
#define TOPK 1024
#define NPQ (BH*NQ)   // 65536
#define NPK (BH*NK)   // 32768

// ---------------- channel LayerNorm (mean/var over C at each (b,pos)) --------
__global__ void chan_ln_k(const float* __restrict__ x, const float* __restrict__ g,
                          const float* __restrict__ bta, float* __restrict__ y,
                          int C, int N, int total) {
  int p = blockIdx.x * blockDim.x + threadIdx.x;
  if (p >= total) return;
  int bi = p / N, sp = p - bi * N;
  const float* xb = x + (size_t)bi * C * N + sp;
  float s = 0.f, s2 = 0.f;
  for (int c = 0; c < C; ++c) { float v = xb[(size_t)c * N]; s += v; s2 += v * v; }
  float m = s / C;
  float var = s2 / C - m * m;
  float inv = 1.f / (sqrtf(fmaxf(var, 0.f)) + 1e-6f);
  float* yb = y + (size_t)bi * C * N + sp;
  for (int c = 0; c < C; ++c) {
    float v = xb[(size_t)c * N];
    yb[(size_t)c * N] = g[c] * (v - m) * inv + bta[c];
  }
}

// ---------------- Y[b,o,n] = sum_c W[o,c] * X[b,c,n] -------------------------
// block 256 = 4 waves; wave w covers 4 consecutive o; lanes = 64 n.
__global__ void gemm_wx_k(const float* __restrict__ W, const float* __restrict__ X,
                          float* __restrict__ Y, int O, int C, int N) {
  int t = threadIdx.x;
  int lane = t & 63, wv = t >> 6;
  int n = blockIdx.x * 64 + lane;
  int ob = blockIdx.y * 16 + wv * 4;
  int b = blockIdx.z;
  const float* Xb = X + (size_t)b * C * N + n;
  float a0 = 0.f, a1 = 0.f, a2 = 0.f, a3 = 0.f;
  for (int c = 0; c < C; ++c) {
    float xv = Xb[(size_t)c * N];
    a0 = fmaf(W[(size_t)(ob + 0) * C + c], xv, a0);
    a1 = fmaf(W[(size_t)(ob + 1) * C + c], xv, a1);
    a2 = fmaf(W[(size_t)(ob + 2) * C + c], xv, a2);
    a3 = fmaf(W[(size_t)(ob + 3) * C + c], xv, a3);
  }
  float* Yb = Y + (size_t)b * O * N + n;
  Yb[(size_t)(ob + 0) * N] = a0;
  Yb[(size_t)(ob + 1) * N] = a1;
  Yb[(size_t)(ob + 2) * N] = a2;
  Yb[(size_t)(ob + 3) * N] = a3;
}

// ---------------- fold heads: (b, ch, n) -> (bh, n, 64), optional L2 norm ----
__global__ void fold_k(const float* __restrict__ src, float* __restrict__ dst,
                       int bstride, int choff, int N, int donorm) {
  __shared__ float tile[64 * 65];
  __shared__ float part[4 * 64];
  __shared__ float invn[64];
  int t = threadIdx.x;
  int lane = t & 63, wv = t >> 6;
  int n0 = blockIdx.x * 64;
  int h = blockIdx.y, bi = blockIdx.z;
  const float* sb = src + (size_t)bi * bstride + (size_t)(choff + h * 64) * N + n0;
  for (int r = 0; r < 16; ++r) {
    int d = r * 4 + wv;
    tile[d * 65 + lane] = sb[(size_t)d * N + lane];
  }
  __syncthreads();
  if (donorm) {
    float s = 0.f;
    for (int r = 0; r < 16; ++r) {
      float v = tile[(wv + 4 * r) * 65 + lane];
      s += v * v;
    }
    part[wv * 64 + lane] = s;
    __syncthreads();
    if (t < 64) {
      float tot = part[t] + part[64 + t] + part[128 + t] + part[192 + t];
      invn[t] = 1.f / fmaxf(sqrtf(tot), 1e-12f);
    }
    __syncthreads();
  }
  float* db = dst + ((size_t)(bi * 8 + h) * N + n0) * 64;
  for (int r = 0; r < 16; ++r) {
    int nn = r * 4 + wv;
    float v = tile[lane * 65 + nn];
    if (donorm) v *= invn[nn];
    db[(size_t)nn * 64 + lane] = v;
  }
}

// ---------------- centroid squared norms -------------------------------------
__global__ void centsq_k(const float* __restrict__ cent, float* __restrict__ csq) {
  int j = blockIdx.x;
  int lane = threadIdx.x;  // blockDim = 64
  float v = cent[j * 64 + lane];
  float s = v * v;
  for (int off = 32; off; off >>= 1) s += __shfl_xor(s, off);
  if (lane == 0) csq[j] = s;
}

// ---------------- nearest-centroid assign ------------------------------------
// block 256 = 4 waves over the SAME 64 points; wave w scans centroids
// [w*256, w*256+256). Cross-wave merge keeps first-index min (ranges ordered).
// MODE 0: write argmin. MODE 1: write L1 distance to nearest centroid.
template <int MODE>
__global__ void assign_k(const float* __restrict__ x, const float* __restrict__ cent,
                         const float* __restrict__ csq, int* __restrict__ aout,
                         float* __restrict__ dout) {
  __shared__ float rd2[256];
  __shared__ int rj[256];
  int t = threadIdx.x, lane = t & 63, wv = t >> 6;
  int p = blockIdx.x * 64 + lane;
  const float4* xr4 = (const float4*)(x + (size_t)p * 64);
  float4 xr[16];
  float xx = 0.f;
  for (int r = 0; r < 16; ++r) {
    xr[r] = xr4[r];
    xx += xr[r].x * xr[r].x + xr[r].y * xr[r].y + xr[r].z * xr[r].z + xr[r].w * xr[r].w;
  }
  float best = 3.4e38f;
  int bestj = 0;
  int j0 = wv * 256;
  for (int j = j0; j < j0 + 256; ++j) {
    const float4* cr = (const float4*)(cent + (size_t)j * 64);
    float dx = 0.f, dy = 0.f, dz = 0.f, dw = 0.f;
    for (int r = 0; r < 16; ++r) {
      float4 c4 = cr[r];
      dx = fmaf(xr[r].x, c4.x, dx);
      dy = fmaf(xr[r].y, c4.y, dy);
      dz = fmaf(xr[r].z, c4.z, dz);
      dw = fmaf(xr[r].w, c4.w, dw);
    }
    float dot = (dx + dy) + (dz + dw);
    float d2 = (xx - 2.f * dot) + csq[j];
    if (d2 < best) { best = d2; bestj = j; }
  }
  rd2[t] = best;
  rj[t] = bestj;
  __syncthreads();
  if (wv == 0) {
    for (int i = 1; i < 4; ++i) {
      float o = rd2[i * 64 + lane];
      int oj = rj[i * 64 + lane];
      if (o < best) { best = o; bestj = oj; }
    }
    if (MODE == 0) {
      aout[p] = bestj;
    } else {
      const float4* cr = (const float4*)(cent + (size_t)bestj * 64);
      float s = 0.f;
      for (int r = 0; r < 16; ++r) {
        float4 c4 = cr[r];
        s += fabsf(c4.x - xr[r].x) + fabsf(c4.y - xr[r].y) +
             fabsf(c4.z - xr[r].z) + fabsf(c4.w - xr[r].w);
      }
      dout[p] = s;
    }
  }
}

// ---------------- segment sum via atomics ------------------------------------
__global__ void segsum_k(const float* __restrict__ x, const int* __restrict__ asg,
                         float* __restrict__ sums, float* __restrict__ cnt) {
  int t = threadIdx.x, lane = t & 63, wv = t >> 6;
  int p = blockIdx.x * 4 + wv;
  int a = asg[p];
  float v = x[(size_t)p * 64 + lane];
  atomicAdd(&sums[a * 64 + lane], v);
  if (lane == 0) atomicAdd(&cnt[a], 1.0f);
}

// ---------------- centroid update --------------------------------------------
__global__ void centup_k(float* __restrict__ cent, const float* __restrict__ sums,
                         const float* __restrict__ cnt) {
  int i = blockIdx.x * 256 + threadIdx.x;  // 65536 total
  int j = i >> 6;
  float c = cnt[j];
  if (c > 0.f) cent[i] = sums[i] / fmaxf(c, 1.f);
}

// ---------------- per-bh top-1024 by descending dist (stable ties) -----------
__global__ void topk_k(const float* __restrict__ dist, int* __restrict__ sel) {
  __shared__ unsigned long long keys[2048];
  int bh = blockIdx.x, t = threadIdx.x;
  for (int i = t; i < 2048; i += 256) {
    float d = dist[bh * 2048 + i];
    unsigned int db = __float_as_uint(d);  // d >= 0 -> monotonic
    keys[i] = ((unsigned long long)db << 32) | (unsigned int)(2047 - i);
  }
  __syncthreads();
  for (int k = 2; k <= 2048; k <<= 1) {
    for (int j = k >> 1; j > 0; j >>= 1) {
      for (int i = t; i < 2048; i += 256) {
        int ixj = i ^ j;
        if (ixj > i) {
          unsigned long long a = keys[i], b = keys[ixj];
          bool up = ((i & k) == 0);
          bool sw = up ? (a < b) : (a > b);  // descending overall
          if (sw) { keys[i] = b; keys[ixj] = a; }
        }
      }
      __syncthreads();
    }
  }
  for (int i = t; i < 1024; i += 256) {
    sel[bh * 1024 + i] = 2047 - (int)(keys[i] & 0xffffffffu);
  }
}

// ---------------- gather selected k/v rows -----------------------------------
__global__ void gather_k(const float* __restrict__ kin, const float* __restrict__ vin,
                         const int* __restrict__ sel, float* __restrict__ kg,
                         float* __restrict__ vg) {
  int t = threadIdx.x, lane = t & 63, wv = t >> 6;
  int row = blockIdx.x * 4 + wv;  // 0..16383
  int bh = row >> 10;
  int src = sel[row];
  size_t si = ((size_t)bh * 2048 + src) * 64 + lane;
  size_t di = (size_t)row * 64 + lane;
  kg[di] = kin[si];
  vg[di] = vin[si];
}

// ---------------- flash attention: 16 heads, 4096 q x 1024 k x 64 d ----------
// block 256 = 4 waves; wave owns 8 q rows; lane = j in QK phase, d in PV phase.
__global__ void attn_k(const float* __restrict__ q, const float* __restrict__ kg,
                       const float* __restrict__ vg, float* __restrict__ o) {
  __shared__ float qt[32 * 68];
  __shared__ float kt[64 * 68];
  __shared__ float vt[64 * 68];
  __shared__ float pb[4 * 8 * 64];
  int t = threadIdx.x, lane = t & 63, wv = t >> 6;
  int bh = blockIdx.y, q0 = blockIdx.x * 32;
  const float* qb = q + ((size_t)bh * 4096 + q0) * 64;
  for (int r = 0; r < 8; ++r) {
    int row = r * 4 + wv;
    qt[row * 68 + lane] = qb[(size_t)row * 64 + lane];
  }
  float acc[8], mst[8], lst[8];
  for (int i = 0; i < 8; ++i) { acc[i] = 0.f; mst[i] = -3.4e38f; lst[i] = 0.f; }
  for (int kt0 = 0; kt0 < 1024; kt0 += 64) {
    __syncthreads();
    const float* kb = kg + ((size_t)bh * 1024 + kt0) * 64;
    const float* vb = vg + ((size_t)bh * 1024 + kt0) * 64;
    for (int r = 0; r < 16; ++r) {
      int row = r * 4 + wv;
      kt[row * 68 + lane] = kb[(size_t)row * 64 + lane];
      vt[row * 68 + lane] = vb[(size_t)row * 64 + lane];
    }
    __syncthreads();
    for (int rq = 0; rq < 8; ++rq) {
      int qrow = wv * 8 + rq;
      float sx = 0.f, sy = 0.f, sz = 0.f, sw = 0.f;
      const float4* krow = (const float4*)&kt[lane * 68];
      const float4* qr4 = (const float4*)&qt[qrow * 68];
      for (int r = 0; r < 16; ++r) {
        float4 k4 = krow[r];
        float4 q4 = qr4[r];
        sx = fmaf(q4.x, k4.x, sx);
        sy = fmaf(q4.y, k4.y, sy);
        sz = fmaf(q4.z, k4.z, sz);
        sw = fmaf(q4.w, k4.w, sw);
      }
      float s = (sx + sy) + (sz + sw);
      float mx = s;
      for (int off = 32; off; off >>= 1) mx = fmaxf(mx, __shfl_xor(mx, off));
      float mnew = fmaxf(mst[rq], mx);
      float pv = __expf(s - mnew);
      float ps = pv;
      for (int off = 32; off; off >>= 1) ps += __shfl_xor(ps, off);
      float corr = __expf(mst[rq] - mnew);
      lst[rq] = lst[rq] * corr + ps;
      mst[rq] = mnew;
      pb[(wv * 8 + rq) * 64 + lane] = pv;
      float a = acc[rq] * corr;
      const float4* pr = (const float4*)&pb[(wv * 8 + rq) * 64];
      for (int r = 0; r < 16; ++r) {
        float4 p4 = pr[r];
        a = fmaf(p4.x, vt[(r * 4 + 0) * 68 + lane], a);
        a = fmaf(p4.y, vt[(r * 4 + 1) * 68 + lane], a);
        a = fmaf(p4.z, vt[(r * 4 + 2) * 68 + lane], a);
        a = fmaf(p4.w, vt[(r * 4 + 3) * 68 + lane], a);
      }
      acc[rq] = a;
    }
  }
  float* ob = o + ((size_t)bh * 4096 + q0) * 64;
  for (int rq = 0; rq < 8; ++rq) {
    int qrow = wv * 8 + rq;
    ob[(size_t)qrow * 64 + lane] = acc[rq] / lst[rq];
  }
}

// ---------------- (bh, n, d) -> (b, h*64+d, n) transpose ---------------------
__global__ void trans_k(const float* __restrict__ att, float* __restrict__ out3) {
  __shared__ float tile[64 * 65];
  int t = threadIdx.x, lane = t & 63, wv = t >> 6;
  int n0 = blockIdx.x * 64, h = blockIdx.y, bi = blockIdx.z;
  const float* ab = att + (((size_t)(bi * 8 + h)) * 4096 + n0) * 64;
  for (int r = 0; r < 16; ++r) {
    int nn = r * 4 + wv;
    tile[nn * 65 + lane] = ab[(size_t)nn * 64 + lane];
  }
  __syncthreads();
  float* ob = out3 + ((size_t)bi * 512 + h * 64) * 4096 + n0;
  for (int r = 0; r < 16; ++r) {
    int dch = r * 4 + wv;
    ob[(size_t)dch * 4096 + lane] = tile[lane * 65 + dch];
  }
}

// ---------------- final LN + gamma*ln + residual -----------------------------
__global__ void final_k(const float* __restrict__ y, const float* __restrict__ g,
                        const float* __restrict__ bta, const float* __restrict__ gamma,
                        const float* __restrict__ qs, float* __restrict__ out) {
  int p = blockIdx.x * blockDim.x + threadIdx.x;
  if (p >= BB * NQ) return;
  int bi = p >> 12, sp = p & 4095;
  const float* yb = y + (size_t)bi * CDIM * NQ + sp;
  float s = 0.f, s2 = 0.f;
  for (int c = 0; c < CDIM; ++c) { float v = yb[(size_t)c * NQ]; s += v; s2 += v * v; }
  float m = s / CDIM;
  float var = s2 / CDIM - m * m;
  float inv = 1.f / (sqrtf(fmaxf(var, 0.f)) + 1e-6f);
  float gm = gamma[0];
  const float* qb = qs + (size_t)bi * CDIM * NQ + sp;
  float* ob = out + (size_t)bi * CDIM * NQ + sp;
  for (int c = 0; c < CDIM; ++c) {
    float v = yb[(size_t)c * NQ];
    float ln = g[c] * (v - m) * inv + bta[c];
    ob[(size_t)c * NQ] = gm * ln + qb[(size_t)c * NQ];
  }
}

extern "C" void kernel_launch(void* const* d_in, const int* in_sizes, int n_in,
                              void* d_out, int out_size, void* d_ws, size_t ws_size,
                              hipStream_t stream) {
  const float* qsrc = (const float*)d_in[0];
  const float* ctx = (const float*)d_in[1];
  const float* w_q = (const float*)d_in[2];
  const float* w_kv = (const float*)d_in[3];
  const float* w_out = (const float*)d_in[4];
  const float* cn_g = (const float*)d_in[5];
  const float* cn_b = (const float*)d_in[6];
  const float* qn_g = (const float*)d_in[7];
  const float* qn_b = (const float*)d_in[8];
  const float* on_g = (const float*)d_in[9];
  const float* on_b = (const float*)d_in[10];
  const float* gamma = (const float*)d_in[11];

  // scratch layout (floats); total 22,267,904 floats = 89.1 MB
  if (ws_size < (size_t)22267904 * 4) return;
  float* ws = (float*)d_ws;
  float* ctxln = ws;                      // 1,048,576
  float* kv = ctxln + 1048576;            // 4,194,304
  float* qsln = kv + 4194304;             // 2,097,152
  float* q3 = qsln + 2097152;             // 4,194,304
  float* qbuf = q3 + 4194304;             // 4,194,304
  float* kbuf = qbuf + 4194304;           // 2,097,152
  float* vbuf = kbuf + 2097152;           // 2,097,152
  float* cent = vbuf + 2097152;           // 65,536
  float* csq = cent + 65536;              // 1,024
  float* sums = csq + 1024;               // 65,536
  float* cnt = sums + 65536;              // 1,024 (contiguous after sums)
  int* asg = (int*)(cnt + 1024);          // 65,536
  float* dist = (float*)(asg + 65536);    // 32,768
  int* sel = (int*)(dist + 32768);        // 16,384
  float* kg = (float*)(sel + 16384);      // 1,048,576
  float* vg = kg + 1048576;               // 1,048,576
  float* attno = q3;                      // reuse (q3 dead after qbuf)
  float* out3 = kv;                       // reuse (kv dead after k/v fold)
  float* ybuf = qsln;                     // reuse (qsln dead after q3)

  // 1. channel LayerNorms
  chan_ln_k<<<(BB * NK + 255) / 256, 256, 0, stream>>>(ctx, cn_g, cn_b, ctxln, CDIM, NK, BB * NK);
  chan_ln_k<<<(BB * NQ + 255) / 256, 256, 0, stream>>>(qsrc, qn_g, qn_b, qsln, CDIM, NQ, BB * NQ);
  // 2. projections
  gemm_wx_k<<<dim3(NK / 64, 1024 / 16, BB), 256, 0, stream>>>(w_kv, ctxln, kv, 1024, CDIM, NK);
  gemm_wx_k<<<dim3(NQ / 64, 512 / 16, BB), 256, 0, stream>>>(w_q, qsln, q3, 512, CDIM, NQ);
  // 3. fold heads (+L2-normalize q,k)
  fold_k<<<dim3(NQ / 64, 8, BB), 256, 0, stream>>>(q3, qbuf, 512 * NQ, 0, NQ, 1);
  fold_k<<<dim3(NK / 64, 8, BB), 256, 0, stream>>>(kv, kbuf, 1024 * NK, 0, NK, 1);
  fold_k<<<dim3(NK / 64, 8, BB), 256, 0, stream>>>(kv, vbuf, 1024 * NK, 512, NK, 0);
  // 4. k-means (init = first 1024 q rows)
  hipMemcpyAsync(cent, qbuf, 65536 * sizeof(float), hipMemcpyDeviceToDevice, stream);
  for (int it = 0; it < 4; ++it) {
    centsq_k<<<1024, 64, 0, stream>>>(cent, csq);
    hipMemsetAsync(sums, 0, (65536 + 1024) * sizeof(float), stream);
    assign_k<0><<<NPQ / 64, 256, 0, stream>>>(qbuf, cent, csq, asg, nullptr);
    segsum_k<<<NPQ / 4, 256, 0, stream>>>(qbuf, asg, sums, cnt);
    centup_k<<<65536 / 256, 256, 0, stream>>>(cent, sums, cnt);
  }
  // 5. score keys: L1 distance to nearest centroid, then per-head top-1024
  centsq_k<<<1024, 64, 0, stream>>>(cent, csq);
  assign_k<1><<<NPK / 64, 256, 0, stream>>>(kbuf, cent, csq, nullptr, dist);
  topk_k<<<BH, 256, 0, stream>>>(dist, sel);
  gather_k<<<BH * TOPK / 4, 256, 0, stream>>>(kbuf, vbuf, sel, kg, vg);
  // 6. attention
  attn_k<<<dim3(NQ / 32, BH), 256, 0, stream>>>(qbuf, kg, vg, attno);
  // 7. un-fold + output projection
  trans_k<<<dim3(NQ / 64, 8, BB), 256, 0, stream>>>(attno, out3);
  gemm_wx_k<<<dim3(NQ / 64, 256 / 16, BB), 256, 0, stream>>>(w_out, out3, ybuf, 256, 512, NQ);
  // 8. final LN + residual
  final_k<<<(BB * NQ + 255) / 256, 256, 0, stream>>>(ybuf, on_g, on_b, gamma, qsrc, (float*)d_out);
}

// Round 2
// 3230.973 us; speedup vs baseline: 2.2707x; 2.2707x over previous
//
#include <hip/hip_runtime.h>
#include <math.h>

#define BB 2
#define CDIM 256
#define NQ 4096   // 16*16*16
#define NK 2048   // 8*16*16
#define BH 16
#define TOPK 1024
#define NPQ (BH*NQ)   // 65536
#define NPK (BH*NK)   // 32768

typedef __attribute__((ext_vector_type(8))) short bfx8;
typedef __attribute__((ext_vector_type(4))) float fx4;
typedef __attribute__((ext_vector_type(4))) unsigned short us4;

__device__ inline unsigned short f2bf(float x) {
  unsigned u = __float_as_uint(x);
  return (unsigned short)((u + 0x7fffu + ((u >> 16) & 1u)) >> 16);
}

// ---------------- channel LayerNorm (mean/var over C at each (b,pos)) --------
__global__ void chan_ln_k(const float* __restrict__ x, const float* __restrict__ g,
                          const float* __restrict__ bta, float* __restrict__ y,
                          int C, int N, int total) {
  int p = blockIdx.x * blockDim.x + threadIdx.x;
  if (p >= total) return;
  int bi = p / N, sp = p - bi * N;
  const float* xb = x + (size_t)bi * C * N + sp;
  float s = 0.f, s2 = 0.f;
  for (int c = 0; c < C; ++c) { float v = xb[(size_t)c * N]; s += v; s2 += v * v; }
  float m = s / C;
  float var = s2 / C - m * m;
  float inv = 1.f / (sqrtf(fmaxf(var, 0.f)) + 1e-6f);
  float* yb = y + (size_t)bi * C * N + sp;
  for (int c = 0; c < C; ++c) {
    float v = xb[(size_t)c * N];
    yb[(size_t)c * N] = g[c] * (v - m) * inv + bta[c];
  }
}

// ---------------- Y[b,o,n] = sum_c W[o,c] * X[b,c,n] -------------------------
__global__ void gemm_wx_k(const float* __restrict__ W, const float* __restrict__ X,
                          float* __restrict__ Y, int O, int C, int N) {
  int t = threadIdx.x;
  int lane = t & 63, wv = t >> 6;
  int n = blockIdx.x * 64 + lane;
  int ob = blockIdx.y * 16 + wv * 4;
  int b = blockIdx.z;
  const float* Xb = X + (size_t)b * C * N + n;
  float a0 = 0.f, a1 = 0.f, a2 = 0.f, a3 = 0.f;
  for (int c = 0; c < C; ++c) {
    float xv = Xb[(size_t)c * N];
    a0 = fmaf(W[(size_t)(ob + 0) * C + c], xv, a0);
    a1 = fmaf(W[(size_t)(ob + 1) * C + c], xv, a1);
    a2 = fmaf(W[(size_t)(ob + 2) * C + c], xv, a2);
    a3 = fmaf(W[(size_t)(ob + 3) * C + c], xv, a3);
  }
  float* Yb = Y + (size_t)b * O * N + n;
  Yb[(size_t)(ob + 0) * N] = a0;
  Yb[(size_t)(ob + 1) * N] = a1;
  Yb[(size_t)(ob + 2) * N] = a2;
  Yb[(size_t)(ob + 3) * N] = a3;
}

// ---------------- fold heads: (b, ch, n) -> (bh, n, 64), optional L2 norm ----
__global__ void fold_k(const float* __restrict__ src, float* __restrict__ dst,
                       int bstride, int choff, int N, int donorm) {
  __shared__ float tile[64 * 65];
  __shared__ float part[4 * 64];
  __shared__ float invn[64];
  int t = threadIdx.x;
  int lane = t & 63, wv = t >> 6;
  int n0 = blockIdx.x * 64;
  int h = blockIdx.y, bi = blockIdx.z;
  const float* sb = src + (size_t)bi * bstride + (size_t)(choff + h * 64) * N + n0;
  for (int r = 0; r < 16; ++r) {
    int d = r * 4 + wv;
    tile[d * 65 + lane] = sb[(size_t)d * N + lane];
  }
  __syncthreads();
  if (donorm) {
    float s = 0.f;
    for (int r = 0; r < 16; ++r) {
      float v = tile[(wv + 4 * r) * 65 + lane];
      s += v * v;
    }
    part[wv * 64 + lane] = s;
    __syncthreads();
    if (t < 64) {
      float tot = part[t] + part[64 + t] + part[128 + t] + part[192 + t];
      invn[t] = 1.f / fmaxf(sqrtf(tot), 1e-12f);
    }
    __syncthreads();
  }
  float* db = dst + ((size_t)(bi * 8 + h) * N + n0) * 64;
  for (int r = 0; r < 16; ++r) {
    int nn = r * 4 + wv;
    float v = tile[lane * 65 + nn];
    if (donorm) v *= invn[nn];
    db[(size_t)nn * 64 + lane] = v;
  }
}

// ---------------- centroid squared norms -------------------------------------
__global__ void centsq_k(const float* __restrict__ cent, float* __restrict__ csq) {
  int j = blockIdx.x;
  int lane = threadIdx.x;  // blockDim = 64
  float v = cent[j * 64 + lane];
  float s = v * v;
  for (int off = 32; off; off >>= 1) s += __shfl_xor(s, off);
  if (lane == 0) csq[j] = s;
}

// ---------------- nearest-centroid assign ------------------------------------
template <int MODE>
__global__ void assign_k(const float* __restrict__ x, const float* __restrict__ cent,
                         const float* __restrict__ csq, int* __restrict__ aout,
                         float* __restrict__ dout) {
  __shared__ float rd2[256];
  __shared__ int rj[256];
  int t = threadIdx.x, lane = t & 63, wv = t >> 6;
  int p = blockIdx.x * 64 + lane;
  const float4* xr4 = (const float4*)(x + (size_t)p * 64);
  float4 xr[16];
  float xx = 0.f;
  for (int r = 0; r < 16; ++r) {
    xr[r] = xr4[r];
    xx += xr[r].x * xr[r].x + xr[r].y * xr[r].y + xr[r].z * xr[r].z + xr[r].w * xr[r].w;
  }
  float best = 3.4e38f;
  int bestj = 0;
  int j0 = wv * 256;
  for (int j = j0; j < j0 + 256; ++j) {
    const float4* cr = (const float4*)(cent + (size_t)j * 64);
    float dx = 0.f, dy = 0.f, dz = 0.f, dw = 0.f;
    for (int r = 0; r < 16; ++r) {
      float4 c4 = cr[r];
      dx = fmaf(xr[r].x, c4.x, dx);
      dy = fmaf(xr[r].y, c4.y, dy);
      dz = fmaf(xr[r].z, c4.z, dz);
      dw = fmaf(xr[r].w, c4.w, dw);
    }
    float dot = (dx + dy) + (dz + dw);
    float d2 = (xx - 2.f * dot) + csq[j];
    if (d2 < best) { best = d2; bestj = j; }
  }
  rd2[t] = best;
  rj[t] = bestj;
  __syncthreads();
  if (wv == 0) {
    for (int i = 1; i < 4; ++i) {
      float o = rd2[i * 64 + lane];
      int oj = rj[i * 64 + lane];
      if (o < best) { best = o; bestj = oj; }
    }
    if (MODE == 0) {
      aout[p] = bestj;
    } else {
      const float4* cr = (const float4*)(cent + (size_t)bestj * 64);
      float s = 0.f;
      for (int r = 0; r < 16; ++r) {
        float4 c4 = cr[r];
        s += fabsf(c4.x - xr[r].x) + fabsf(c4.y - xr[r].y) +
             fabsf(c4.z - xr[r].z) + fabsf(c4.w - xr[r].w);
      }
      dout[p] = s;
    }
  }
}

// ---------------- segment sum via atomics ------------------------------------
__global__ void segsum_k(const float* __restrict__ x, const int* __restrict__ asg,
                         float* __restrict__ sums, float* __restrict__ cnt) {
  int t = threadIdx.x, lane = t & 63, wv = t >> 6;
  int p = blockIdx.x * 4 + wv;
  int a = asg[p];
  float v = x[(size_t)p * 64 + lane];
  atomicAdd(&sums[a * 64 + lane], v);
  if (lane == 0) atomicAdd(&cnt[a], 1.0f);
}

// ---------------- centroid update --------------------------------------------
__global__ void centup_k(float* __restrict__ cent, const float* __restrict__ sums,
                         const float* __restrict__ cnt) {
  int i = blockIdx.x * 256 + threadIdx.x;  // 65536 total
  int j = i >> 6;
  float c = cnt[j];
  if (c > 0.f) cent[i] = sums[i] / fmaxf(c, 1.f);
}

// ---------------- per-bh top-1024 by descending dist (stable ties) -----------
__global__ void topk_k(const float* __restrict__ dist, int* __restrict__ sel) {
  __shared__ unsigned long long keys[2048];
  int bh = blockIdx.x, t = threadIdx.x;
  for (int i = t; i < 2048; i += 256) {
    float d = dist[bh * 2048 + i];
    unsigned int db = __float_as_uint(d);  // d >= 0 -> monotonic
    keys[i] = ((unsigned long long)db << 32) | (unsigned int)(2047 - i);
  }
  __syncthreads();
  for (int k = 2; k <= 2048; k <<= 1) {
    for (int j = k >> 1; j > 0; j >>= 1) {
      for (int i = t; i < 2048; i += 256) {
        int ixj = i ^ j;
        if (ixj > i) {
          unsigned long long a = keys[i], b = keys[ixj];
          bool up = ((i & k) == 0);
          bool sw = up ? (a < b) : (a > b);  // descending overall
          if (sw) { keys[i] = b; keys[ixj] = a; }
        }
      }
      __syncthreads();
    }
  }
  for (int i = t; i < 1024; i += 256) {
    sel[bh * 1024 + i] = 2047 - (int)(keys[i] & 0xffffffffu);
  }
}

// ---------------- gather selected rows -> kh (bf16 row-major), vT (bf16 d-major)
__global__ void gatherb_k(const float* __restrict__ kbuf, const float* __restrict__ vbuf,
                          const int* __restrict__ sel, unsigned short* __restrict__ kh,
                          unsigned short* __restrict__ vT) {
  __shared__ unsigned short tile[64][66];
  int t = threadIdx.x, lane = t & 63, wv = t >> 6;
  int bh = blockIdx.y, i0 = blockIdx.x * 64;
  for (int r = 0; r < 16; ++r) {
    int i = r * 4 + wv;
    int src = sel[bh * 1024 + i0 + i];
    float kvv = kbuf[((size_t)bh * 2048 + src) * 64 + lane];
    kh[((size_t)bh * 1024 + i0 + i) * 64 + lane] = f2bf(kvv);
    float vv = vbuf[((size_t)bh * 2048 + src) * 64 + lane];
    tile[i][lane] = f2bf(vv);
  }
  __syncthreads();
  for (int r = 0; r < 16; ++r) {
    int d = r * 4 + wv;
    vT[((size_t)bh * 64 + d) * 1024 + i0 + lane] = tile[lane][d];
  }
}

// ---------------- f32 -> bf16 bulk convert (n multiple of 1024) --------------
__global__ void tobf_k(const float* __restrict__ x, unsigned short* __restrict__ y) {
  int i = blockIdx.x * 256 + threadIdx.x;
  float4 v = ((const float4*)x)[i];
  us4 o = {f2bf(v.x), f2bf(v.y), f2bf(v.z), f2bf(v.w)};
  *(us4*)(y + (size_t)i * 4) = o;
}

// ---------------- MFMA flash attention ---------------------------------------
// block 256 = 4 waves; wave owns 16 q rows; swapped QK^T (S^T: row=k, col=q).
// q,k unit-norm => s in [-1,1] => no online max needed: p = exp(s).
__global__ __launch_bounds__(256) void attn_mfma_k(
    const unsigned short* __restrict__ qh, const unsigned short* __restrict__ kh,
    const unsigned short* __restrict__ vT, float* __restrict__ o) {
  __shared__ unsigned short plds[4][16][72];
  int t = threadIdx.x, lane = t & 63, wv = t >> 6;
  int lq = lane & 15, lg = lane >> 4;
  int bh = blockIdx.y;
  int q0 = blockIdx.x * 64 + wv * 16;
  const unsigned short* qbase = qh + ((size_t)bh * 4096 + q0 + lq) * 64;
  bfx8 qf0 = *(const bfx8*)(qbase + lg * 8);
  bfx8 qf1 = *(const bfx8*)(qbase + 32 + lg * 8);
  fx4 acc[4];
  for (int nt = 0; nt < 4; ++nt) acc[nt] = (fx4){0.f, 0.f, 0.f, 0.f};
  float lsum = 0.f;
  const unsigned short* kbase = kh + (size_t)bh * 1024 * 64;
  const unsigned short* vbase = vT + (size_t)bh * 64 * 1024;
  for (int kt0 = 0; kt0 < 1024; kt0 += 64) {
    // S^T tiles: T[k=64][q=16]; A = K rows, B = Q rows (both d-sliced)
    fx4 s[4];
    for (int mt = 0; mt < 4; ++mt) {
      const unsigned short* kr = kbase + (size_t)(kt0 + mt * 16 + lq) * 64 + lg * 8;
      bfx8 a0 = *(const bfx8*)(kr);
      bfx8 a1 = *(const bfx8*)(kr + 32);
      fx4 c = (fx4){0.f, 0.f, 0.f, 0.f};
      c = __builtin_amdgcn_mfma_f32_16x16x32_bf16(a0, qf0, c, 0, 0, 0);
      c = __builtin_amdgcn_mfma_f32_16x16x32_bf16(a1, qf1, c, 0, 0, 0);
      s[mt] = c;
    }
    __syncthreads();  // previous iteration's P reads complete before overwrite
    for (int mt = 0; mt < 4; ++mt) {
      float p0 = __expf(s[mt].x), p1 = __expf(s[mt].y);
      float p2 = __expf(s[mt].z), p3 = __expf(s[mt].w);
      lsum += (p0 + p1) + (p2 + p3);
      us4 pk = {f2bf(p0), f2bf(p1), f2bf(p2), f2bf(p3)};
      *(us4*)&plds[wv][lq][mt * 16 + lg * 4] = pk;
    }
    __syncthreads();  // P visible
    bfx8 pa0 = *(const bfx8*)&plds[wv][lq][lg * 8];
    bfx8 pa1 = *(const bfx8*)&plds[wv][lq][32 + lg * 8];
    for (int nt = 0; nt < 4; ++nt) {
      const unsigned short* vr = vbase + (size_t)(nt * 16 + lq) * 1024 + kt0 + lg * 8;
      bfx8 b0 = *(const bfx8*)(vr);
      bfx8 b1 = *(const bfx8*)(vr + 32);
      acc[nt] = __builtin_amdgcn_mfma_f32_16x16x32_bf16(pa0, b0, acc[nt], 0, 0, 0);
      acc[nt] = __builtin_amdgcn_mfma_f32_16x16x32_bf16(pa1, b1, acc[nt], 0, 0, 0);
    }
  }
  lsum += __shfl_xor(lsum, 16);
  lsum += __shfl_xor(lsum, 32);
  float* ob = o + ((size_t)bh * 4096 + q0) * 64;
  for (int r = 0; r < 4; ++r) {
    float inv = 1.f / __shfl(lsum, lg * 4 + r);
    for (int nt = 0; nt < 4; ++nt)
      ob[(size_t)(lg * 4 + r) * 64 + nt * 16 + lq] = acc[nt][r] * inv;
  }
}

// ---------------- (bh, n, d) -> (b, h*64+d, n) transpose ---------------------
__global__ void trans_k(const float* __restrict__ att, float* __restrict__ out3) {
  __shared__ float tile[64 * 65];
  int t = threadIdx.x, lane = t & 63, wv = t >> 6;
  int n0 = blockIdx.x * 64, h = blockIdx.y, bi = blockIdx.z;
  const float* ab = att + (((size_t)(bi * 8 + h)) * 4096 + n0) * 64;
  for (int r = 0; r < 16; ++r) {
    int nn = r * 4 + wv;
    tile[nn * 65 + lane] = ab[(size_t)nn * 64 + lane];
  }
  __syncthreads();
  float* ob = out3 + ((size_t)bi * 512 + h * 64) * 4096 + n0;
  for (int r = 0; r < 16; ++r) {
    int dch = r * 4 + wv;
    ob[(size_t)dch * 4096 + lane] = tile[lane * 65 + dch];
  }
}

// ---------------- final LN + gamma*ln + residual -----------------------------
__global__ void final_k(const float* __restrict__ y, const float* __restrict__ g,
                        const float* __restrict__ bta, const float* __restrict__ gamma,
                        const float* __restrict__ qs, float* __restrict__ out) {
  int p = blockIdx.x * blockDim.x + threadIdx.x;
  if (p >= BB * NQ) return;
  int bi = p >> 12, sp = p & 4095;
  const float* yb = y + (size_t)bi * CDIM * NQ + sp;
  float s = 0.f, s2 = 0.f;
  for (int c = 0; c < CDIM; ++c) { float v = yb[(size_t)c * NQ]; s += v; s2 += v * v; }
  float m = s / CDIM;
  float var = s2 / CDIM - m * m;
  float inv = 1.f / (sqrtf(fmaxf(var, 0.f)) + 1e-6f);
  float gm = gamma[0];
  const float* qb = qs + (size_t)bi * CDIM * NQ + sp;
  float* ob = out + (size_t)bi * CDIM * NQ + sp;
  for (int c = 0; c < CDIM; ++c) {
    float v = yb[(size_t)c * NQ];
    float ln = g[c] * (v - m) * inv + bta[c];
    ob[(size_t)c * NQ] = gm * ln + qb[(size_t)c * NQ];
  }
}

extern "C" void kernel_launch(void* const* d_in, const int* in_sizes, int n_in,
                              void* d_out, int out_size, void* d_ws, size_t ws_size,
                              hipStream_t stream) {
  const float* qsrc = (const float*)d_in[0];
  const float* ctx = (const float*)d_in[1];
  const float* w_q = (const float*)d_in[2];
  const float* w_kv = (const float*)d_in[3];
  const float* w_out = (const float*)d_in[4];
  const float* cn_g = (const float*)d_in[5];
  const float* cn_b = (const float*)d_in[6];
  const float* qn_g = (const float*)d_in[7];
  const float* qn_b = (const float*)d_in[8];
  const float* on_g = (const float*)d_in[9];
  const float* on_b = (const float*)d_in[10];
  const float* gamma = (const float*)d_in[11];

  // scratch layout (floats); total 22,267,904 floats = 89.1 MB
  if (ws_size < (size_t)22267904 * 4) return;
  float* ws = (float*)d_ws;
  float* ctxln = ws;                      // 1,048,576 (reused: kh+vT bf16 later)
  float* kv = ctxln + 1048576;            // 4,194,304
  float* qsln = kv + 4194304;             // 2,097,152
  float* q3 = qsln + 2097152;             // 4,194,304
  float* qbuf = q3 + 4194304;             // 4,194,304
  float* kbuf = qbuf + 4194304;           // 2,097,152
  float* vbuf = kbuf + 2097152;           // 2,097,152
  float* cent = vbuf + 2097152;           // 65,536
  float* csq = cent + 65536;              // 1,024
  float* sums = csq + 1024;               // 65,536
  float* cnt = sums + 65536;              // 1,024
  int* asg = (int*)(cnt + 1024);          // 65,536
  float* dist = (float*)(asg + 65536);    // 32,768
  int* sel = (int*)(dist + 32768);        // 16,384
  float* kgreg = (float*)(sel + 16384);   // 2,097,152 (bf16 qh region)
  unsigned short* qh = (unsigned short*)kgreg;   // 4M bf16 = 8 MB
  unsigned short* kh = (unsigned short*)ctxln;   // 1M bf16 (after ctxln dead)
  unsigned short* vT = kh + 1048576;             // 1M bf16
  float* attno = q3;                      // reuse (q3 dead after qh conversion)
  float* out3 = kv;                       // reuse (kv dead after k/v fold)
  float* ybuf = qsln;                     // reuse (qsln dead after q3)

  // 1. channel LayerNorms
  chan_ln_k<<<(BB * NK + 255) / 256, 256, 0, stream>>>(ctx, cn_g, cn_b, ctxln, CDIM, NK, BB * NK);
  chan_ln_k<<<(BB * NQ + 255) / 256, 256, 0, stream>>>(qsrc, qn_g, qn_b, qsln, CDIM, NQ, BB * NQ);
  // 2. projections
  gemm_wx_k<<<dim3(NK / 64, 1024 / 16, BB), 256, 0, stream>>>(w_kv, ctxln, kv, 1024, CDIM, NK);
  gemm_wx_k<<<dim3(NQ / 64, 512 / 16, BB), 256, 0, stream>>>(w_q, qsln, q3, 512, CDIM, NQ);
  // 3. fold heads (+L2-normalize q,k)
  fold_k<<<dim3(NQ / 64, 8, BB), 256, 0, stream>>>(q3, qbuf, 512 * NQ, 0, NQ, 1);
  fold_k<<<dim3(NK / 64, 8, BB), 256, 0, stream>>>(kv, kbuf, 1024 * NK, 0, NK, 1);
  fold_k<<<dim3(NK / 64, 8, BB), 256, 0, stream>>>(kv, vbuf, 1024 * NK, 512, NK, 0);
  // 4. k-means (init = first 1024 q rows)
  hipMemcpyAsync(cent, qbuf, 65536 * sizeof(float), hipMemcpyDeviceToDevice, stream);
  for (int it = 0; it < 4; ++it) {
    centsq_k<<<1024, 64, 0, stream>>>(cent, csq);
    hipMemsetAsync(sums, 0, (65536 + 1024) * sizeof(float), stream);
    assign_k<0><<<NPQ / 64, 256, 0, stream>>>(qbuf, cent, csq, asg, nullptr);
    segsum_k<<<NPQ / 4, 256, 0, stream>>>(qbuf, asg, sums, cnt);
    centup_k<<<65536 / 256, 256, 0, stream>>>(cent, sums, cnt);
  }
  // 5. score keys: L1 distance to nearest centroid, then per-head top-1024
  centsq_k<<<1024, 64, 0, stream>>>(cent, csq);
  assign_k<1><<<NPK / 64, 256, 0, stream>>>(kbuf, cent, csq, nullptr, dist);
  topk_k<<<BH, 256, 0, stream>>>(dist, sel);
  // 6. bf16 conversions + gather (kh row-major, vT transposed)
  tobf_k<<<NPQ * 64 / 1024, 256, 0, stream>>>(qbuf, qh);
  gatherb_k<<<dim3(TOPK / 64, BH), 256, 0, stream>>>(kbuf, vbuf, sel, kh, vT);
  // 7. MFMA attention
  attn_mfma_k<<<dim3(NQ / 64, BH), 256, 0, stream>>>(qh, kh, vT, attno);
  // 8. un-fold + output projection
  trans_k<<<dim3(NQ / 64, 8, BB), 256, 0, stream>>>(attno, out3);
  gemm_wx_k<<<dim3(NQ / 64, 256 / 16, BB), 256, 0, stream>>>(w_out, out3, ybuf, 256, 512, NQ);
  // 9. final LN + residual
  final_k<<<(BB * NQ + 255) / 256, 256, 0, stream>>>(ybuf, on_g, on_b, gamma, qsrc, (float*)d_out);
}

// Round 4
// 1622.493 us; speedup vs baseline: 4.5218x; 1.9914x over previous
//
#include <hip/hip_runtime.h>
#include <math.h>

#define BB 2
#define CDIM 256
#define NQ 4096   // 16*16*16
#define NK 2048   // 8*16*16
#define BH 16
#define TOPK 1024
#define NPQ (BH*NQ)   // 65536
#define NPK (BH*NK)   // 32768

typedef __attribute__((ext_vector_type(8))) short bfx8;
typedef __attribute__((ext_vector_type(8))) _Float16 hfx8;
typedef __attribute__((ext_vector_type(4))) float fx4;
typedef __attribute__((ext_vector_type(4))) unsigned short us4;

__device__ inline unsigned short f2bf(float x) {
  unsigned u = __float_as_uint(x);
  return (unsigned short)((u + 0x7fffu + ((u >> 16) & 1u)) >> 16);
}
__device__ inline unsigned short f2h_bits(float x) {
  _Float16 h = (_Float16)x;
  unsigned short u;
  __builtin_memcpy(&u, &h, 2);
  return u;
}
__device__ inline float h_bits2f(unsigned short u) {
  _Float16 h;
  __builtin_memcpy(&h, &u, 2);
  return (float)h;
}

// ---------------- channel LayerNorm (mean/var over C at each (b,pos)) --------
__global__ void chan_ln_k(const float* __restrict__ x, const float* __restrict__ g,
                          const float* __restrict__ bta, float* __restrict__ y,
                          int C, int N, int total) {
  int p = blockIdx.x * blockDim.x + threadIdx.x;
  if (p >= total) return;
  int bi = p / N, sp = p - bi * N;
  const float* xb = x + (size_t)bi * C * N + sp;
  float s = 0.f, s2 = 0.f;
  for (int c = 0; c < C; ++c) { float v = xb[(size_t)c * N]; s += v; s2 += v * v; }
  float m = s / C;
  float var = s2 / C - m * m;
  float inv = 1.f / (sqrtf(fmaxf(var, 0.f)) + 1e-6f);
  float* yb = y + (size_t)bi * C * N + sp;
  for (int c = 0; c < C; ++c) {
    float v = xb[(size_t)c * N];
    yb[(size_t)c * N] = g[c] * (v - m) * inv + bta[c];
  }
}

// ---------------- Y[b,o,n] = sum_c W[o,c] * X[b,c,n] -------------------------
__global__ void gemm_wx_k(const float* __restrict__ W, const float* __restrict__ X,
                          float* __restrict__ Y, int O, int C, int N) {
  int t = threadIdx.x;
  int lane = t & 63, wv = t >> 6;
  int n = blockIdx.x * 64 + lane;
  int ob = blockIdx.y * 16 + wv * 4;
  int b = blockIdx.z;
  const float* Xb = X + (size_t)b * C * N + n;
  float a0 = 0.f, a1 = 0.f, a2 = 0.f, a3 = 0.f;
  for (int c = 0; c < C; ++c) {
    float xv = Xb[(size_t)c * N];
    a0 = fmaf(W[(size_t)(ob + 0) * C + c], xv, a0);
    a1 = fmaf(W[(size_t)(ob + 1) * C + c], xv, a1);
    a2 = fmaf(W[(size_t)(ob + 2) * C + c], xv, a2);
    a3 = fmaf(W[(size_t)(ob + 3) * C + c], xv, a3);
  }
  float* Yb = Y + (size_t)b * O * N + n;
  Yb[(size_t)(ob + 0) * N] = a0;
  Yb[(size_t)(ob + 1) * N] = a1;
  Yb[(size_t)(ob + 2) * N] = a2;
  Yb[(size_t)(ob + 3) * N] = a3;
}

// ---------------- fold heads: (b, ch, n) -> (bh, n, 64), optional L2 norm ----
__global__ void fold_k(const float* __restrict__ src, float* __restrict__ dst,
                       int bstride, int choff, int N, int donorm) {
  __shared__ float tile[64 * 65];
  __shared__ float part[4 * 64];
  __shared__ float invn[64];
  int t = threadIdx.x;
  int lane = t & 63, wv = t >> 6;
  int n0 = blockIdx.x * 64;
  int h = blockIdx.y, bi = blockIdx.z;
  const float* sb = src + (size_t)bi * bstride + (size_t)(choff + h * 64) * N + n0;
  for (int r = 0; r < 16; ++r) {
    int d = r * 4 + wv;
    tile[d * 65 + lane] = sb[(size_t)d * N + lane];
  }
  __syncthreads();
  if (donorm) {
    float s = 0.f;
    for (int r = 0; r < 16; ++r) {
      float v = tile[(wv + 4 * r) * 65 + lane];
      s += v * v;
    }
    part[wv * 64 + lane] = s;
    __syncthreads();
    if (t < 64) {
      float tot = part[t] + part[64 + t] + part[128 + t] + part[192 + t];
      invn[t] = 1.f / fmaxf(sqrtf(tot), 1e-12f);
    }
    __syncthreads();
  }
  float* db = dst + ((size_t)(bi * 8 + h) * N + n0) * 64;
  for (int r = 0; r < 16; ++r) {
    int nn = r * 4 + wv;
    float v = tile[lane * 65 + nn];
    if (donorm) v *= invn[nn];
    db[(size_t)nn * 64 + lane] = v;
  }
}

// ---------------- f32 -> split f16 (hi + lo*2048) ----------------------------
__global__ void tof2_k(const float* __restrict__ x, unsigned short* __restrict__ yh,
                       unsigned short* __restrict__ yl) {
  int i = blockIdx.x * 256 + threadIdx.x;
  float4 v = ((const float4*)x)[i];
  us4 h = {f2h_bits(v.x), f2h_bits(v.y), f2h_bits(v.z), f2h_bits(v.w)};
  us4 l = {f2h_bits((v.x - h_bits2f(h.x)) * 2048.f),
           f2h_bits((v.y - h_bits2f(h.y)) * 2048.f),
           f2h_bits((v.z - h_bits2f(h.z)) * 2048.f),
           f2h_bits((v.w - h_bits2f(h.w)) * 2048.f)};
  *(us4*)(yh + (size_t)i * 4) = h;
  *(us4*)(yl + (size_t)i * 4) = l;
}

// ---------------- centroid prep: csq (f32), -2c split f16 --------------------
__global__ void centprep_k(const float* __restrict__ cent, float* __restrict__ csq,
                           unsigned short* __restrict__ cb2h, unsigned short* __restrict__ cb2l) {
  int j = blockIdx.x, lane = threadIdx.x;  // blockDim = 64
  float c = cent[j * 64 + lane];
  float s = c * c;
  for (int off = 32; off; off >>= 1) s += __shfl_xor(s, off);
  if (lane == 0) csq[j] = s;
  float m2 = -2.f * c;
  unsigned short h = f2h_bits(m2);
  cb2h[j * 64 + lane] = h;
  cb2l[j * 64 + lane] = f2h_bits((m2 - h_bits2f(h)) * 2048.f);
}

// ---------------- MFMA nearest-centroid assign (f16 split) -------------------
// d2eff = cc[j] - 2*dot(c_j, x_p); x = xh + xl/2048, -2c = ch + cl/2048.
// hi acc: ch.xh (+csq); lo acc: ch.xl + cl.xh (each term carries one 2048);
// d2 = hi + lo/2048. Residual error ~1e-6 (xl.cl + f16 rounding of xl).
__global__ __launch_bounds__(256) void assign_mfma_k(
    const unsigned short* __restrict__ xh, const unsigned short* __restrict__ xl,
    const unsigned short* __restrict__ cb2h, const unsigned short* __restrict__ cb2l,
    const float* __restrict__ csq, int* __restrict__ aout) {
  int t = threadIdx.x, lane = t & 63, wv = t >> 6;
  int lq = lane & 15, lg = lane >> 4;
  int p0 = blockIdx.x * 64 + wv * 16;
  const unsigned short* xb = xh + (size_t)(p0 + lq) * 64;
  const unsigned short* xlb = xl + (size_t)(p0 + lq) * 64;
  hfx8 bh0 = *(const hfx8*)(xb + lg * 8);
  hfx8 bh1 = *(const hfx8*)(xb + 32 + lg * 8);
  hfx8 bl0 = *(const hfx8*)(xlb + lg * 8);
  hfx8 bl1 = *(const hfx8*)(xlb + 32 + lg * 8);
  float best = 3.4e38f;
  int bestj = 0;
  for (int j0 = 0; j0 < 1024; j0 += 64) {
    for (int mt = 0; mt < 4; ++mt) {
      int jr = j0 + mt * 16;
      const unsigned short* ar = cb2h + (size_t)(jr + lq) * 64 + lg * 8;
      const unsigned short* al = cb2l + (size_t)(jr + lq) * 64 + lg * 8;
      hfx8 ah0 = *(const hfx8*)(ar);
      hfx8 ah1 = *(const hfx8*)(ar + 32);
      hfx8 al0 = *(const hfx8*)(al);
      hfx8 al1 = *(const hfx8*)(al + 32);
      fx4 chi = *(const fx4*)(csq + jr + lg * 4);
      chi = __builtin_amdgcn_mfma_f32_16x16x32_f16(ah0, bh0, chi, 0, 0, 0);
      chi = __builtin_amdgcn_mfma_f32_16x16x32_f16(ah1, bh1, chi, 0, 0, 0);
      fx4 clo = (fx4){0.f, 0.f, 0.f, 0.f};
      clo = __builtin_amdgcn_mfma_f32_16x16x32_f16(ah0, bl0, clo, 0, 0, 0);
      clo = __builtin_amdgcn_mfma_f32_16x16x32_f16(ah1, bl1, clo, 0, 0, 0);
      clo = __builtin_amdgcn_mfma_f32_16x16x32_f16(al0, bh0, clo, 0, 0, 0);
      clo = __builtin_amdgcn_mfma_f32_16x16x32_f16(al1, bh1, clo, 0, 0, 0);
      for (int r = 0; r < 4; ++r) {
        int j = jr + lg * 4 + r;
        float d2 = chi[r] + clo[r] * (1.f / 2048.f);
        if (d2 < best) { best = d2; bestj = j; }  // ascending j per lane
      }
    }
  }
  // merge across lg groups (lanes lq, lq+16, lq+32, lq+48); tie -> lower j
  {
    float o = __shfl_xor(best, 16);
    int oj = __shfl_xor(bestj, 16);
    if (o < best || (o == best && oj < bestj)) { best = o; bestj = oj; }
    o = __shfl_xor(best, 32);
    oj = __shfl_xor(bestj, 32);
    if (o < best || (o == best && oj < bestj)) { best = o; bestj = oj; }
  }
  if (lg == 0) aout[p0 + lq] = bestj;
}

// ---------------- exact f32 L1 distance to assigned centroid -----------------
__global__ void dist_k(const float* __restrict__ x, const float* __restrict__ cent,
                       const int* __restrict__ asg, float* __restrict__ dout) {
  int t = threadIdx.x, lane = t & 63, wv = t >> 6;
  int p = blockIdx.x * 4 + wv;
  int a = asg[p];
  float v = fabsf(cent[(size_t)a * 64 + lane] - x[(size_t)p * 64 + lane]);
  for (int off = 32; off; off >>= 1) v += __shfl_xor(v, off);
  if (lane == 0) dout[p] = v;
}

// ---------------- segment sum via atomics ------------------------------------
__global__ void segsum_k(const float* __restrict__ x, const int* __restrict__ asg,
                         float* __restrict__ sums, float* __restrict__ cnt) {
  int t = threadIdx.x, lane = t & 63, wv = t >> 6;
  int p = blockIdx.x * 4 + wv;
  int a = asg[p];
  float v = x[(size_t)p * 64 + lane];
  atomicAdd(&sums[a * 64 + lane], v);
  if (lane == 0) atomicAdd(&cnt[a], 1.0f);
}

// ---------------- centroid update --------------------------------------------
__global__ void centup_k(float* __restrict__ cent, const float* __restrict__ sums,
                         const float* __restrict__ cnt) {
  int i = blockIdx.x * 256 + threadIdx.x;  // 65536 total
  int j = i >> 6;
  float c = cnt[j];
  if (c > 0.f) cent[i] = sums[i] / fmaxf(c, 1.f);
}

// ---------------- per-bh top-1024 by descending dist (stable ties) -----------
__global__ void topk_k(const float* __restrict__ dist, int* __restrict__ sel) {
  __shared__ unsigned long long keys[2048];
  int bh = blockIdx.x, t = threadIdx.x;
  for (int i = t; i < 2048; i += 256) {
    float d = dist[bh * 2048 + i];
    unsigned int db = __float_as_uint(d);  // d >= 0 -> monotonic
    keys[i] = ((unsigned long long)db << 32) | (unsigned int)(2047 - i);
  }
  __syncthreads();
  for (int k = 2; k <= 2048; k <<= 1) {
    for (int j = k >> 1; j > 0; j >>= 1) {
      for (int i = t; i < 2048; i += 256) {
        int ixj = i ^ j;
        if (ixj > i) {
          unsigned long long a = keys[i], b = keys[ixj];
          bool up = ((i & k) == 0);
          bool sw = up ? (a < b) : (a > b);  // descending overall
          if (sw) { keys[i] = b; keys[ixj] = a; }
        }
      }
      __syncthreads();
    }
  }
  for (int i = t; i < 1024; i += 256) {
    sel[bh * 1024 + i] = 2047 - (int)(keys[i] & 0xffffffffu);
  }
}

// ---------------- gather selected rows -> kh (bf16 row-major), vT (bf16 d-major)
__global__ void gatherb_k(const float* __restrict__ kbuf, const float* __restrict__ vbuf,
                          const int* __restrict__ sel, unsigned short* __restrict__ kh,
                          unsigned short* __restrict__ vT) {
  __shared__ unsigned short tile[64][66];
  int t = threadIdx.x, lane = t & 63, wv = t >> 6;
  int bh = blockIdx.y, i0 = blockIdx.x * 64;
  for (int r = 0; r < 16; ++r) {
    int i = r * 4 + wv;
    int src = sel[bh * 1024 + i0 + i];
    float kvv = kbuf[((size_t)bh * 2048 + src) * 64 + lane];
    kh[((size_t)bh * 1024 + i0 + i) * 64 + lane] = f2bf(kvv);
    float vv = vbuf[((size_t)bh * 2048 + src) * 64 + lane];
    tile[i][lane] = f2bf(vv);
  }
  __syncthreads();
  for (int r = 0; r < 16; ++r) {
    int d = r * 4 + wv;
    vT[((size_t)bh * 64 + d) * 1024 + i0 + lane] = tile[lane][d];
  }
}

// ---------------- f32 -> bf16 bulk convert -----------------------------------
__global__ void tobf_k(const float* __restrict__ x, unsigned short* __restrict__ y) {
  int i = blockIdx.x * 256 + threadIdx.x;
  float4 v = ((const float4*)x)[i];
  us4 o = {f2bf(v.x), f2bf(v.y), f2bf(v.z), f2bf(v.w)};
  *(us4*)(y + (size_t)i * 4) = o;
}

// ---------------- MFMA flash attention ---------------------------------------
__global__ __launch_bounds__(256) void attn_mfma_k(
    const unsigned short* __restrict__ qh, const unsigned short* __restrict__ kh,
    const unsigned short* __restrict__ vT, float* __restrict__ o) {
  __shared__ unsigned short plds[4][16][72];
  int t = threadIdx.x, lane = t & 63, wv = t >> 6;
  int lq = lane & 15, lg = lane >> 4;
  int bh = blockIdx.y;
  int q0 = blockIdx.x * 64 + wv * 16;
  const unsigned short* qbase = qh + ((size_t)bh * 4096 + q0 + lq) * 64;
  bfx8 qf0 = *(const bfx8*)(qbase + lg * 8);
  bfx8 qf1 = *(const bfx8*)(qbase + 32 + lg * 8);
  fx4 acc[4];
  for (int nt = 0; nt < 4; ++nt) acc[nt] = (fx4){0.f, 0.f, 0.f, 0.f};
  float lsum = 0.f;
  const unsigned short* kbase = kh + (size_t)bh * 1024 * 64;
  const unsigned short* vbase = vT + (size_t)bh * 64 * 1024;
  for (int kt0 = 0; kt0 < 1024; kt0 += 64) {
    fx4 s[4];
    for (int mt = 0; mt < 4; ++mt) {
      const unsigned short* kr = kbase + (size_t)(kt0 + mt * 16 + lq) * 64 + lg * 8;
      bfx8 a0 = *(const bfx8*)(kr);
      bfx8 a1 = *(const bfx8*)(kr + 32);
      fx4 c = (fx4){0.f, 0.f, 0.f, 0.f};
      c = __builtin_amdgcn_mfma_f32_16x16x32_bf16(a0, qf0, c, 0, 0, 0);
      c = __builtin_amdgcn_mfma_f32_16x16x32_bf16(a1, qf1, c, 0, 0, 0);
      s[mt] = c;
    }
    __syncthreads();
    for (int mt = 0; mt < 4; ++mt) {
      float p0 = __expf(s[mt].x), p1 = __expf(s[mt].y);
      float p2 = __expf(s[mt].z), p3 = __expf(s[mt].w);
      lsum += (p0 + p1) + (p2 + p3);
      us4 pk = {f2bf(p0), f2bf(p1), f2bf(p2), f2bf(p3)};
      *(us4*)&plds[wv][lq][mt * 16 + lg * 4] = pk;
    }
    __syncthreads();
    bfx8 pa0 = *(const bfx8*)&plds[wv][lq][lg * 8];
    bfx8 pa1 = *(const bfx8*)&plds[wv][lq][32 + lg * 8];
    for (int nt = 0; nt < 4; ++nt) {
      const unsigned short* vr = vbase + (size_t)(nt * 16 + lq) * 1024 + kt0 + lg * 8;
      bfx8 b0 = *(const bfx8*)(vr);
      bfx8 b1 = *(const bfx8*)(vr + 32);
      acc[nt] = __builtin_amdgcn_mfma_f32_16x16x32_bf16(pa0, b0, acc[nt], 0, 0, 0);
      acc[nt] = __builtin_amdgcn_mfma_f32_16x16x32_bf16(pa1, b1, acc[nt], 0, 0, 0);
    }
  }
  lsum += __shfl_xor(lsum, 16);
  lsum += __shfl_xor(lsum, 32);
  float* ob = o + ((size_t)bh * 4096 + q0) * 64;
  for (int r = 0; r < 4; ++r) {
    float inv = 1.f / __shfl(lsum, lg * 4 + r);
    for (int nt = 0; nt < 4; ++nt)
      ob[(size_t)(lg * 4 + r) * 64 + nt * 16 + lq] = acc[nt][r] * inv;
  }
}

// ---------------- (bh, n, d) -> (b, h*64+d, n) transpose ---------------------
__global__ void trans_k(const float* __restrict__ att, float* __restrict__ out3) {
  __shared__ float tile[64 * 65];
  int t = threadIdx.x, lane = t & 63, wv = t >> 6;
  int n0 = blockIdx.x * 64, h = blockIdx.y, bi = blockIdx.z;
  const float* ab = att + (((size_t)(bi * 8 + h)) * 4096 + n0) * 64;
  for (int r = 0; r < 16; ++r) {
    int nn = r * 4 + wv;
    tile[nn * 65 + lane] = ab[(size_t)nn * 64 + lane];
  }
  __syncthreads();
  float* ob = out3 + ((size_t)bi * 512 + h * 64) * 4096 + n0;
  for (int r = 0; r < 16; ++r) {
    int dch = r * 4 + wv;
    ob[(size_t)dch * 4096 + lane] = tile[lane * 65 + dch];
  }
}

// ---------------- final LN + gamma*ln + residual -----------------------------
__global__ void final_k(const float* __restrict__ y, const float* __restrict__ g,
                        const float* __restrict__ bta, const float* __restrict__ gamma,
                        const float* __restrict__ qs, float* __restrict__ out) {
  int p = blockIdx.x * blockDim.x + threadIdx.x;
  if (p >= BB * NQ) return;
  int bi = p >> 12, sp = p & 4095;
  const float* yb = y + (size_t)bi * CDIM * NQ + sp;
  float s = 0.f, s2 = 0.f;
  for (int c = 0; c < CDIM; ++c) { float v = yb[(size_t)c * NQ]; s += v; s2 += v * v; }
  float m = s / CDIM;
  float var = s2 / CDIM - m * m;
  float inv = 1.f / (sqrtf(fmaxf(var, 0.f)) + 1e-6f);
  float gm = gamma[0];
  const float* qb = qs + (size_t)bi * CDIM * NQ + sp;
  float* ob = out + (size_t)bi * CDIM * NQ + sp;
  for (int c = 0; c < CDIM; ++c) {
    float v = yb[(size_t)c * NQ];
    float ln = g[c] * (v - m) * inv + bta[c];
    ob[(size_t)c * NQ] = gm * ln + qb[(size_t)c * NQ];
  }
}

extern "C" void kernel_launch(void* const* d_in, const int* in_sizes, int n_in,
                              void* d_out, int out_size, void* d_ws, size_t ws_size,
                              hipStream_t stream) {
  const float* qsrc = (const float*)d_in[0];
  const float* ctx = (const float*)d_in[1];
  const float* w_q = (const float*)d_in[2];
  const float* w_kv = (const float*)d_in[3];
  const float* w_out = (const float*)d_in[4];
  const float* cn_g = (const float*)d_in[5];
  const float* cn_b = (const float*)d_in[6];
  const float* qn_g = (const float*)d_in[7];
  const float* qn_b = (const float*)d_in[8];
  const float* on_g = (const float*)d_in[9];
  const float* on_b = (const float*)d_in[10];
  const float* gamma = (const float*)d_in[11];

  // scratch layout (floats); total 22,267,904 floats = 89.1 MB
  if (ws_size < (size_t)22267904 * 4) return;
  float* ws = (float*)d_ws;
  float* ctxln = ws;                      // 1,048,576 f (later: kh+vT bf16)
  float* kv = ctxln + 1048576;            // 4,194,304 f (later: kbh/kbl, then out3)
  float* qsln = kv + 4194304;             // 2,097,152 f (later: cb2h/l, then ybuf)
  float* q3 = qsln + 2097152;             // 4,194,304 f (later: qbh/qbl, then attno)
  float* qbuf = q3 + 4194304;             // 4,194,304 f
  float* kbuf = qbuf + 4194304;           // 2,097,152 f
  float* vbuf = kbuf + 2097152;           // 2,097,152 f
  float* cent = vbuf + 2097152;           // 65,536 f
  float* csq = cent + 65536;              // 1,024 f
  float* sums = csq + 1024;               // 65,536 f
  float* cnt = sums + 65536;              // 1,024 f
  int* asg = (int*)(cnt + 1024);          // 65,536 i
  float* dist = (float*)(asg + 65536);    // 32,768 f
  int* sel = (int*)(dist + 32768);        // 16,384 i
  float* kgreg = (float*)(sel + 16384);   // 2,097,152 f (qh bf16)
  unsigned short* qh = (unsigned short*)kgreg;   // 4M bf16
  unsigned short* kh = (unsigned short*)ctxln;   // 1M bf16
  unsigned short* vT = kh + 1048576;             // 1M bf16
  unsigned short* qbh = (unsigned short*)q3;     // 4M f16 (q split hi)
  unsigned short* qbl = qbh + (size_t)NPQ * 64;  // 4M f16 (q split lo*2048)
  unsigned short* kbh = (unsigned short*)kv;     // 2M f16 (k split hi)
  unsigned short* kbl = kbh + (size_t)NPK * 64;  // 2M f16 (k split lo*2048)
  unsigned short* cb2h = (unsigned short*)qsln;  // 64K f16 (-2c hi)
  unsigned short* cb2l = cb2h + 65536;           // 64K f16 (-2c lo*2048)
  float* attno = q3;                      // reuse (qbh/qbl dead after assigns)
  float* out3 = kv;                       // reuse (kbh/kbl dead after assigns)
  float* ybuf = qsln;                     // reuse (cb2 dead after assigns)

  // 1. channel LayerNorms
  chan_ln_k<<<(BB * NK + 255) / 256, 256, 0, stream>>>(ctx, cn_g, cn_b, ctxln, CDIM, NK, BB * NK);
  chan_ln_k<<<(BB * NQ + 255) / 256, 256, 0, stream>>>(qsrc, qn_g, qn_b, qsln, CDIM, NQ, BB * NQ);
  // 2. projections
  gemm_wx_k<<<dim3(NK / 64, 1024 / 16, BB), 256, 0, stream>>>(w_kv, ctxln, kv, 1024, CDIM, NK);
  gemm_wx_k<<<dim3(NQ / 64, 512 / 16, BB), 256, 0, stream>>>(w_q, qsln, q3, 512, CDIM, NQ);
  // 3. fold heads (+L2-normalize q,k)   NOTE: q3/kv/qsln still live here
  fold_k<<<dim3(NQ / 64, 8, BB), 256, 0, stream>>>(q3, qbuf, 512 * NQ, 0, NQ, 1);
  fold_k<<<dim3(NK / 64, 8, BB), 256, 0, stream>>>(kv, kbuf, 1024 * NK, 0, NK, 1);
  fold_k<<<dim3(NK / 64, 8, BB), 256, 0, stream>>>(kv, vbuf, 1024 * NK, 512, NK, 0);
  // 4. split-f16 conversions (q3, kv regions now reusable)
  tof2_k<<<NPQ * 64 / 1024, 256, 0, stream>>>(qbuf, qbh, qbl);
  tof2_k<<<NPK * 64 / 1024, 256, 0, stream>>>(kbuf, kbh, kbl);
  // 5. k-means (init = first 1024 q rows)
  hipMemcpyAsync(cent, qbuf, 65536 * sizeof(float), hipMemcpyDeviceToDevice, stream);
  for (int it = 0; it < 4; ++it) {
    centprep_k<<<1024, 64, 0, stream>>>(cent, csq, cb2h, cb2l);
    hipMemsetAsync(sums, 0, (65536 + 1024) * sizeof(float), stream);
    assign_mfma_k<<<NPQ / 64, 256, 0, stream>>>(qbh, qbl, cb2h, cb2l, csq, asg);
    segsum_k<<<NPQ / 4, 256, 0, stream>>>(qbuf, asg, sums, cnt);
    centup_k<<<65536 / 256, 256, 0, stream>>>(cent, sums, cnt);
  }
  // 6. score keys: argmin (MFMA) -> exact f32 L1 dist -> per-head top-1024
  centprep_k<<<1024, 64, 0, stream>>>(cent, csq, cb2h, cb2l);
  assign_mfma_k<<<NPK / 64, 256, 0, stream>>>(kbh, kbl, cb2h, cb2l, csq, asg);
  dist_k<<<NPK / 4, 256, 0, stream>>>(kbuf, cent, asg, dist);
  topk_k<<<BH, 256, 0, stream>>>(dist, sel);
  // 7. bf16 conversions + gather (kh row-major, vT transposed)
  tobf_k<<<NPQ * 64 / 1024, 256, 0, stream>>>(qbuf, qh);
  gatherb_k<<<dim3(TOPK / 64, BH), 256, 0, stream>>>(kbuf, vbuf, sel, kh, vT);
  // 8. MFMA attention
  attn_mfma_k<<<dim3(NQ / 64, BH), 256, 0, stream>>>(qh, kh, vT, attno);
  // 9. un-fold + output projection
  trans_k<<<dim3(NQ / 64, 8, BB), 256, 0, stream>>>(attno, out3);
  gemm_wx_k<<<dim3(NQ / 64, 256 / 16, BB), 256, 0, stream>>>(w_out, out3, ybuf, 256, 512, NQ);
  // 10. final LN + residual
  final_k<<<(BB * NQ + 255) / 256, 256, 0, stream>>>(ybuf, on_g, on_b, gamma, qsrc, (float*)d_out);
}

// Round 5
// 1256.038 us; speedup vs baseline: 5.8411x; 1.2918x over previous
//
#include <hip/hip_runtime.h>
#include <math.h>

#define BB 2
#define CDIM 256
#define NQ 4096   // 16*16*16
#define NK 2048   // 8*16*16
#define BH 16
#define TOPK 1024
#define NPQ (BH*NQ)   // 65536
#define NPK (BH*NK)   // 32768

typedef __attribute__((ext_vector_type(8))) short bfx8;
typedef __attribute__((ext_vector_type(8))) _Float16 hfx8;
typedef __attribute__((ext_vector_type(4))) float fx4;
typedef __attribute__((ext_vector_type(4))) unsigned short us4;

__device__ inline unsigned short f2bf(float x) {
  unsigned u = __float_as_uint(x);
  return (unsigned short)((u + 0x7fffu + ((u >> 16) & 1u)) >> 16);
}
__device__ inline unsigned short f2h_bits(float x) {
  _Float16 h = (_Float16)x;
  unsigned short u;
  __builtin_memcpy(&u, &h, 2);
  return u;
}
__device__ inline float h_bits2f(unsigned short u) {
  _Float16 h;
  __builtin_memcpy(&h, &u, 2);
  return (float)h;
}

// ------- channel LayerNorm -> transposed split-f16 [b][n][C] (hi, lo*2048) ---
__global__ void chan_ln_tsplit_k(const float* __restrict__ x, const float* __restrict__ g,
                                 const float* __restrict__ bta,
                                 unsigned short* __restrict__ yh, unsigned short* __restrict__ yl,
                                 int C, int N, int total) {
  int p = blockIdx.x * blockDim.x + threadIdx.x;
  if (p >= total) return;
  int bi = p / N, sp = p - bi * N;
  const float* xb = x + (size_t)bi * C * N + sp;
  float s = 0.f, s2 = 0.f;
  for (int c = 0; c < C; ++c) { float v = xb[(size_t)c * N]; s += v; s2 += v * v; }
  float m = s / C;
  float var = s2 / C - m * m;
  float inv = 1.f / (sqrtf(fmaxf(var, 0.f)) + 1e-6f);
  unsigned short* oh = yh + (size_t)p * C;
  unsigned short* ol = yl + (size_t)p * C;
  for (int c = 0; c < C; c += 4) {
    us4 hh, ll;
#pragma unroll
    for (int j = 0; j < 4; ++j) {
      float v = xb[(size_t)(c + j) * N];
      float ln = g[c + j] * (v - m) * inv + bta[c + j];
      unsigned short hb = f2h_bits(ln);
      hh[j] = hb;
      ll[j] = f2h_bits((ln - h_bits2f(hb)) * 2048.f);
    }
    *(us4*)(oh + c) = hh;
    *(us4*)(ol + c) = ll;
  }
}

// ------- MFMA GEMM: Y[b][o][n] = sum_c W[o][c] * Xt[b][n][c] -----------------
// Xt pre-split f16 (hi + lo*2048); W split in-register. 3-pass split product.
__global__ __launch_bounds__(256) void gemm_mfma_k(
    const float* __restrict__ W, const unsigned short* __restrict__ Xh,
    const unsigned short* __restrict__ Xl, float* __restrict__ Y,
    int O, int C, int N) {
  int t = threadIdx.x, lane = t & 63, wv = t >> 6;
  int lq = lane & 15, lg = lane >> 4;
  int n0 = blockIdx.x * 64, o0 = blockIdx.y * 64 + wv * 16;
  int b = blockIdx.z;
  const unsigned short* xbh = Xh + ((size_t)b * N + n0) * C;
  const unsigned short* xbl = Xl + ((size_t)b * N + n0) * C;
  const float* wr = W + (size_t)(o0 + lq) * C;
  fx4 ahi[4], alo[4];
  for (int nt = 0; nt < 4; ++nt) {
    ahi[nt] = (fx4){0.f, 0.f, 0.f, 0.f};
    alo[nt] = (fx4){0.f, 0.f, 0.f, 0.f};
  }
  for (int k0 = 0; k0 < C; k0 += 32) {
    float4 w0 = *(const float4*)(wr + k0 + lg * 8);
    float4 w1 = *(const float4*)(wr + k0 + lg * 8 + 4);
    float wv8[8] = {w0.x, w0.y, w0.z, w0.w, w1.x, w1.y, w1.z, w1.w};
    hfx8 ah, al;
#pragma unroll
    for (int i = 0; i < 8; ++i) {
      _Float16 h = (_Float16)wv8[i];
      ah[i] = h;
      al[i] = (_Float16)((wv8[i] - (float)h) * 2048.f);
    }
#pragma unroll
    for (int nt = 0; nt < 4; ++nt) {
      const unsigned short* bph = xbh + (size_t)(nt * 16 + lq) * C + k0 + lg * 8;
      const unsigned short* bpl = xbl + (size_t)(nt * 16 + lq) * C + k0 + lg * 8;
      hfx8 bh = *(const hfx8*)bph;
      hfx8 bl = *(const hfx8*)bpl;
      ahi[nt] = __builtin_amdgcn_mfma_f32_16x16x32_f16(ah, bh, ahi[nt], 0, 0, 0);
      alo[nt] = __builtin_amdgcn_mfma_f32_16x16x32_f16(al, bh, alo[nt], 0, 0, 0);
      alo[nt] = __builtin_amdgcn_mfma_f32_16x16x32_f16(ah, bl, alo[nt], 0, 0, 0);
    }
  }
  float* yb = Y + ((size_t)b * O + o0) * N + n0;
#pragma unroll
  for (int nt = 0; nt < 4; ++nt)
#pragma unroll
    for (int r = 0; r < 4; ++r)
      yb[(size_t)(lg * 4 + r) * N + nt * 16 + lq] = ahi[nt][r] + alo[nt][r] * (1.f / 2048.f);
}

// ---------------- fold heads: (b, ch, n) -> (bh, n, 64), optional L2 norm ----
__global__ void fold_k(const float* __restrict__ src, float* __restrict__ dst,
                       int bstride, int choff, int N, int donorm) {
  __shared__ float tile[64 * 65];
  __shared__ float part[4 * 64];
  __shared__ float invn[64];
  int t = threadIdx.x;
  int lane = t & 63, wv = t >> 6;
  int n0 = blockIdx.x * 64;
  int h = blockIdx.y, bi = blockIdx.z;
  const float* sb = src + (size_t)bi * bstride + (size_t)(choff + h * 64) * N + n0;
  for (int r = 0; r < 16; ++r) {
    int d = r * 4 + wv;
    tile[d * 65 + lane] = sb[(size_t)d * N + lane];
  }
  __syncthreads();
  if (donorm) {
    float s = 0.f;
    for (int r = 0; r < 16; ++r) {
      float v = tile[(wv + 4 * r) * 65 + lane];
      s += v * v;
    }
    part[wv * 64 + lane] = s;
    __syncthreads();
    if (t < 64) {
      float tot = part[t] + part[64 + t] + part[128 + t] + part[192 + t];
      invn[t] = 1.f / fmaxf(sqrtf(tot), 1e-12f);
    }
    __syncthreads();
  }
  float* db = dst + ((size_t)(bi * 8 + h) * N + n0) * 64;
  for (int r = 0; r < 16; ++r) {
    int nn = r * 4 + wv;
    float v = tile[lane * 65 + nn];
    if (donorm) v *= invn[nn];
    db[(size_t)nn * 64 + lane] = v;
  }
}

// ---------------- f32 -> split f16 (hi + lo*2048) ----------------------------
__global__ void tof2_k(const float* __restrict__ x, unsigned short* __restrict__ yh,
                       unsigned short* __restrict__ yl) {
  int i = blockIdx.x * 256 + threadIdx.x;
  float4 v = ((const float4*)x)[i];
  us4 h = {f2h_bits(v.x), f2h_bits(v.y), f2h_bits(v.z), f2h_bits(v.w)};
  us4 l = {f2h_bits((v.x - h_bits2f(h.x)) * 2048.f),
           f2h_bits((v.y - h_bits2f(h.y)) * 2048.f),
           f2h_bits((v.z - h_bits2f(h.z)) * 2048.f),
           f2h_bits((v.w - h_bits2f(h.w)) * 2048.f)};
  *(us4*)(yh + (size_t)i * 4) = h;
  *(us4*)(yl + (size_t)i * 4) = l;
}

// ---------------- centroid prep: csq (f32), -2c split f16 --------------------
__global__ void centprep_k(const float* __restrict__ cent, float* __restrict__ csq,
                           unsigned short* __restrict__ cb2h, unsigned short* __restrict__ cb2l) {
  int j = blockIdx.x, lane = threadIdx.x;  // blockDim = 64
  float c = cent[j * 64 + lane];
  float s = c * c;
  for (int off = 32; off; off >>= 1) s += __shfl_xor(s, off);
  if (lane == 0) csq[j] = s;
  float m2 = -2.f * c;
  unsigned short h = f2h_bits(m2);
  cb2h[j * 64 + lane] = h;
  cb2l[j * 64 + lane] = f2h_bits((m2 - h_bits2f(h)) * 2048.f);
}

// ---------------- MFMA nearest-centroid assign (f16 split) -------------------
__global__ __launch_bounds__(256) void assign_mfma_k(
    const unsigned short* __restrict__ xh, const unsigned short* __restrict__ xl,
    const unsigned short* __restrict__ cb2h, const unsigned short* __restrict__ cb2l,
    const float* __restrict__ csq, int* __restrict__ aout) {
  int t = threadIdx.x, lane = t & 63, wv = t >> 6;
  int lq = lane & 15, lg = lane >> 4;
  int p0 = blockIdx.x * 64 + wv * 16;
  const unsigned short* xb = xh + (size_t)(p0 + lq) * 64;
  const unsigned short* xlb = xl + (size_t)(p0 + lq) * 64;
  hfx8 bh0 = *(const hfx8*)(xb + lg * 8);
  hfx8 bh1 = *(const hfx8*)(xb + 32 + lg * 8);
  hfx8 bl0 = *(const hfx8*)(xlb + lg * 8);
  hfx8 bl1 = *(const hfx8*)(xlb + 32 + lg * 8);
  float best = 3.4e38f;
  int bestj = 0;
  for (int j0 = 0; j0 < 1024; j0 += 64) {
    for (int mt = 0; mt < 4; ++mt) {
      int jr = j0 + mt * 16;
      const unsigned short* ar = cb2h + (size_t)(jr + lq) * 64 + lg * 8;
      const unsigned short* al = cb2l + (size_t)(jr + lq) * 64 + lg * 8;
      hfx8 ah0 = *(const hfx8*)(ar);
      hfx8 ah1 = *(const hfx8*)(ar + 32);
      hfx8 al0 = *(const hfx8*)(al);
      hfx8 al1 = *(const hfx8*)(al + 32);
      fx4 chi = *(const fx4*)(csq + jr + lg * 4);
      chi = __builtin_amdgcn_mfma_f32_16x16x32_f16(ah0, bh0, chi, 0, 0, 0);
      chi = __builtin_amdgcn_mfma_f32_16x16x32_f16(ah1, bh1, chi, 0, 0, 0);
      fx4 clo = (fx4){0.f, 0.f, 0.f, 0.f};
      clo = __builtin_amdgcn_mfma_f32_16x16x32_f16(ah0, bl0, clo, 0, 0, 0);
      clo = __builtin_amdgcn_mfma_f32_16x16x32_f16(ah1, bl1, clo, 0, 0, 0);
      clo = __builtin_amdgcn_mfma_f32_16x16x32_f16(al0, bh0, clo, 0, 0, 0);
      clo = __builtin_amdgcn_mfma_f32_16x16x32_f16(al1, bh1, clo, 0, 0, 0);
      for (int r = 0; r < 4; ++r) {
        int j = jr + lg * 4 + r;
        float d2 = chi[r] + clo[r] * (1.f / 2048.f);
        if (d2 < best) { best = d2; bestj = j; }  // ascending j per lane
      }
    }
  }
  {
    float o = __shfl_xor(best, 16);
    int oj = __shfl_xor(bestj, 16);
    if (o < best || (o == best && oj < bestj)) { best = o; bestj = oj; }
    o = __shfl_xor(best, 32);
    oj = __shfl_xor(bestj, 32);
    if (o < best || (o == best && oj < bestj)) { best = o; bestj = oj; }
  }
  if (lg == 0) aout[p0 + lq] = bestj;
}

// ---------------- exact f32 L1 distance to assigned centroid -----------------
__global__ void dist_k(const float* __restrict__ x, const float* __restrict__ cent,
                       const int* __restrict__ asg, float* __restrict__ dout) {
  int t = threadIdx.x, lane = t & 63, wv = t >> 6;
  int p = blockIdx.x * 4 + wv;
  int a = asg[p];
  float v = fabsf(cent[(size_t)a * 64 + lane] - x[(size_t)p * 64 + lane]);
  for (int off = 32; off; off >>= 1) v += __shfl_xor(v, off);
  if (lane == 0) dout[p] = v;
}

// ---------------- segment sum via atomics ------------------------------------
__global__ void segsum_k(const float* __restrict__ x, const int* __restrict__ asg,
                         float* __restrict__ sums, float* __restrict__ cnt) {
  int t = threadIdx.x, lane = t & 63, wv = t >> 6;
  int p = blockIdx.x * 4 + wv;
  int a = asg[p];
  float v = x[(size_t)p * 64 + lane];
  atomicAdd(&sums[a * 64 + lane], v);
  if (lane == 0) atomicAdd(&cnt[a], 1.0f);
}

// ---------------- centroid update --------------------------------------------
__global__ void centup_k(float* __restrict__ cent, const float* __restrict__ sums,
                         const float* __restrict__ cnt) {
  int i = blockIdx.x * 256 + threadIdx.x;  // 65536 total
  int j = i >> 6;
  float c = cnt[j];
  if (c > 0.f) cent[i] = sums[i] / fmaxf(c, 1.f);
}

// ---------------- per-bh top-1024 by descending dist (stable ties) -----------
__global__ void topk_k(const float* __restrict__ dist, int* __restrict__ sel) {
  __shared__ unsigned long long keys[2048];
  int bh = blockIdx.x, t = threadIdx.x;
  for (int i = t; i < 2048; i += 256) {
    float d = dist[bh * 2048 + i];
    unsigned int db = __float_as_uint(d);  // d >= 0 -> monotonic
    keys[i] = ((unsigned long long)db << 32) | (unsigned int)(2047 - i);
  }
  __syncthreads();
  for (int k = 2; k <= 2048; k <<= 1) {
    for (int j = k >> 1; j > 0; j >>= 1) {
      for (int i = t; i < 2048; i += 256) {
        int ixj = i ^ j;
        if (ixj > i) {
          unsigned long long a = keys[i], b = keys[ixj];
          bool up = ((i & k) == 0);
          bool sw = up ? (a < b) : (a > b);  // descending overall
          if (sw) { keys[i] = b; keys[ixj] = a; }
        }
      }
      __syncthreads();
    }
  }
  for (int i = t; i < 1024; i += 256) {
    sel[bh * 1024 + i] = 2047 - (int)(keys[i] & 0xffffffffu);
  }
}

// ---------------- gather selected rows -> kh (bf16 row-major), vT (bf16 d-major)
__global__ void gatherb_k(const float* __restrict__ kbuf, const float* __restrict__ vbuf,
                          const int* __restrict__ sel, unsigned short* __restrict__ kh,
                          unsigned short* __restrict__ vT) {
  __shared__ unsigned short tile[64][66];
  int t = threadIdx.x, lane = t & 63, wv = t >> 6;
  int bh = blockIdx.y, i0 = blockIdx.x * 64;
  for (int r = 0; r < 16; ++r) {
    int i = r * 4 + wv;
    int src = sel[bh * 1024 + i0 + i];
    float kvv = kbuf[((size_t)bh * 2048 + src) * 64 + lane];
    kh[((size_t)bh * 1024 + i0 + i) * 64 + lane] = f2bf(kvv);
    float vv = vbuf[((size_t)bh * 2048 + src) * 64 + lane];
    tile[i][lane] = f2bf(vv);
  }
  __syncthreads();
  for (int r = 0; r < 16; ++r) {
    int d = r * 4 + wv;
    vT[((size_t)bh * 64 + d) * 1024 + i0 + lane] = tile[lane][d];
  }
}

// ---------------- f32 -> bf16 bulk convert -----------------------------------
__global__ void tobf_k(const float* __restrict__ x, unsigned short* __restrict__ y) {
  int i = blockIdx.x * 256 + threadIdx.x;
  float4 v = ((const float4*)x)[i];
  us4 o = {f2bf(v.x), f2bf(v.y), f2bf(v.z), f2bf(v.w)};
  *(us4*)(y + (size_t)i * 4) = o;
}

// ---------------- MFMA flash attention; out = split-f16 [b][n][h*64+d] ------
__global__ __launch_bounds__(256) void attn_mfma_k(
    const unsigned short* __restrict__ qh, const unsigned short* __restrict__ kh,
    const unsigned short* __restrict__ vT,
    unsigned short* __restrict__ oh, unsigned short* __restrict__ ol) {
  __shared__ unsigned short plds[4][16][72];
  int t = threadIdx.x, lane = t & 63, wv = t >> 6;
  int lq = lane & 15, lg = lane >> 4;
  int bh = blockIdx.y;
  int q0 = blockIdx.x * 64 + wv * 16;
  const unsigned short* qbase = qh + ((size_t)bh * 4096 + q0 + lq) * 64;
  bfx8 qf0 = *(const bfx8*)(qbase + lg * 8);
  bfx8 qf1 = *(const bfx8*)(qbase + 32 + lg * 8);
  fx4 acc[4];
  for (int nt = 0; nt < 4; ++nt) acc[nt] = (fx4){0.f, 0.f, 0.f, 0.f};
  float lsum = 0.f;
  const unsigned short* kbase = kh + (size_t)bh * 1024 * 64;
  const unsigned short* vbase = vT + (size_t)bh * 64 * 1024;
  for (int kt0 = 0; kt0 < 1024; kt0 += 64) {
    fx4 s[4];
    for (int mt = 0; mt < 4; ++mt) {
      const unsigned short* kr = kbase + (size_t)(kt0 + mt * 16 + lq) * 64 + lg * 8;
      bfx8 a0 = *(const bfx8*)(kr);
      bfx8 a1 = *(const bfx8*)(kr + 32);
      fx4 c = (fx4){0.f, 0.f, 0.f, 0.f};
      c = __builtin_amdgcn_mfma_f32_16x16x32_bf16(a0, qf0, c, 0, 0, 0);
      c = __builtin_amdgcn_mfma_f32_16x16x32_bf16(a1, qf1, c, 0, 0, 0);
      s[mt] = c;
    }
    __syncthreads();
    for (int mt = 0; mt < 4; ++mt) {
      float p0 = __expf(s[mt].x), p1 = __expf(s[mt].y);
      float p2 = __expf(s[mt].z), p3 = __expf(s[mt].w);
      lsum += (p0 + p1) + (p2 + p3);
      us4 pk = {f2bf(p0), f2bf(p1), f2bf(p2), f2bf(p3)};
      *(us4*)&plds[wv][lq][mt * 16 + lg * 4] = pk;
    }
    __syncthreads();
    bfx8 pa0 = *(const bfx8*)&plds[wv][lq][lg * 8];
    bfx8 pa1 = *(const bfx8*)&plds[wv][lq][32 + lg * 8];
    for (int nt = 0; nt < 4; ++nt) {
      const unsigned short* vr = vbase + (size_t)(nt * 16 + lq) * 1024 + kt0 + lg * 8;
      bfx8 b0 = *(const bfx8*)(vr);
      bfx8 b1 = *(const bfx8*)(vr + 32);
      acc[nt] = __builtin_amdgcn_mfma_f32_16x16x32_bf16(pa0, b0, acc[nt], 0, 0, 0);
      acc[nt] = __builtin_amdgcn_mfma_f32_16x16x32_bf16(pa1, b1, acc[nt], 0, 0, 0);
    }
  }
  lsum += __shfl_xor(lsum, 16);
  lsum += __shfl_xor(lsum, 32);
  int bi = bh >> 3, hd = bh & 7;
  for (int r = 0; r < 4; ++r) {
    float inv = 1.f / __shfl(lsum, lg * 4 + r);
    size_t rowb = ((size_t)bi * 4096 + q0 + lg * 4 + r) * 512 + hd * 64;
    for (int nt = 0; nt < 4; ++nt) {
      float val = acc[nt][r] * inv;
      unsigned short hb = f2h_bits(val);
      oh[rowb + nt * 16 + lq] = hb;
      ol[rowb + nt * 16 + lq] = f2h_bits((val - h_bits2f(hb)) * 2048.f);
    }
  }
}

// ---------------- final LN + gamma*ln + residual -----------------------------
__global__ void final_k(const float* __restrict__ y, const float* __restrict__ g,
                        const float* __restrict__ bta, const float* __restrict__ gamma,
                        const float* __restrict__ qs, float* __restrict__ out) {
  int p = blockIdx.x * blockDim.x + threadIdx.x;
  if (p >= BB * NQ) return;
  int bi = p >> 12, sp = p & 4095;
  const float* yb = y + (size_t)bi * CDIM * NQ + sp;
  float s = 0.f, s2 = 0.f;
  for (int c = 0; c < CDIM; ++c) { float v = yb[(size_t)c * NQ]; s += v; s2 += v * v; }
  float m = s / CDIM;
  float var = s2 / CDIM - m * m;
  float inv = 1.f / (sqrtf(fmaxf(var, 0.f)) + 1e-6f);
  float gm = gamma[0];
  const float* qb = qs + (size_t)bi * CDIM * NQ + sp;
  float* ob = out + (size_t)bi * CDIM * NQ + sp;
  for (int c = 0; c < CDIM; ++c) {
    float v = yb[(size_t)c * NQ];
    float ln = g[c] * (v - m) * inv + bta[c];
    ob[(size_t)c * NQ] = gm * ln + qb[(size_t)c * NQ];
  }
}

extern "C" void kernel_launch(void* const* d_in, const int* in_sizes, int n_in,
                              void* d_out, int out_size, void* d_ws, size_t ws_size,
                              hipStream_t stream) {
  const float* qsrc = (const float*)d_in[0];
  const float* ctx = (const float*)d_in[1];
  const float* w_q = (const float*)d_in[2];
  const float* w_kv = (const float*)d_in[3];
  const float* w_out = (const float*)d_in[4];
  const float* cn_g = (const float*)d_in[5];
  const float* cn_b = (const float*)d_in[6];
  const float* qn_g = (const float*)d_in[7];
  const float* qn_b = (const float*)d_in[8];
  const float* on_g = (const float*)d_in[9];
  const float* on_b = (const float*)d_in[10];
  const float* gamma = (const float*)d_in[11];

  // scratch layout (floats); total 22,267,904 floats = 89.1 MB
  if (ws_size < (size_t)22267904 * 4) return;
  float* ws = (float*)d_ws;
  float* r_ctx = ws;                      // 1,048,576 f: ctx split-f16; later kh/vT
  float* r_kv = r_ctx + 1048576;          // 4,194,304 f: kv f32; later kbh/kbl; later attnt split
  float* r_qs = r_kv + 4194304;           // 2,097,152 f: qs split-f16; later cb2h/l; later ybuf
  float* r_q3 = r_qs + 2097152;           // 4,194,304 f: q3 f32; later qbh/qbl
  float* qbuf = r_q3 + 4194304;           // 4,194,304 f
  float* kbuf = qbuf + 4194304;           // 2,097,152 f
  float* vbuf = kbuf + 2097152;           // 2,097,152 f
  float* cent = vbuf + 2097152;           // 65,536 f
  float* csq = cent + 65536;              // 1,024 f
  float* sums = csq + 1024;               // 65,536 f
  float* cnt = sums + 65536;              // 1,024 f
  int* asg = (int*)(cnt + 1024);          // 65,536 i
  float* dist = (float*)(asg + 65536);    // 32,768 f
  int* sel = (int*)(dist + 32768);        // 16,384 i
  float* kgreg = (float*)(sel + 16384);   // 2,097,152 f (qh bf16)

  unsigned short* ctxth = (unsigned short*)r_ctx;   // [b][2048][256] f16 hi
  unsigned short* ctxtl = ctxth + (size_t)BB * NK * CDIM;  // lo
  unsigned short* qsth = (unsigned short*)r_qs;     // [b][4096][256] f16 hi
  unsigned short* qstl = qsth + (size_t)BB * NQ * CDIM;    // lo
  float* kvf = r_kv;                      // [b][1024][2048] f32
  float* q3f = r_q3;                      // [b][512][4096] f32
  unsigned short* qh = (unsigned short*)kgreg;      // 4M bf16
  unsigned short* kh = (unsigned short*)r_ctx;      // 1M bf16 (ctx split dead)
  unsigned short* vT = kh + 1048576;                // 1M bf16
  unsigned short* qbh = (unsigned short*)r_q3;      // 4M f16 (q split hi)
  unsigned short* qbl = qbh + (size_t)NPQ * 64;     // 4M f16 (lo)
  unsigned short* kbh = (unsigned short*)r_kv;      // 2M f16 (k split hi)
  unsigned short* kbl = kbh + (size_t)NPK * 64;     // 2M f16 (lo)
  unsigned short* cb2h = (unsigned short*)r_qs;     // 64K f16 (-2c hi)
  unsigned short* cb2l = cb2h + 65536;              // 64K f16 (lo)
  unsigned short* attnth = (unsigned short*)r_kv;   // [b][4096][512] f16 hi (kb split dead)
  unsigned short* attntl = attnth + (size_t)BB * NQ * 512;  // lo
  float* ybuf = r_qs;                     // [b][256][4096] f32 (cb2 dead)

  // 1. channel LayerNorms -> transposed split-f16
  chan_ln_tsplit_k<<<(BB * NK + 255) / 256, 256, 0, stream>>>(ctx, cn_g, cn_b, ctxth, ctxtl, CDIM, NK, BB * NK);
  chan_ln_tsplit_k<<<(BB * NQ + 255) / 256, 256, 0, stream>>>(qsrc, qn_g, qn_b, qsth, qstl, CDIM, NQ, BB * NQ);
  // 2. MFMA projections
  gemm_mfma_k<<<dim3(NK / 64, 1024 / 64, BB), 256, 0, stream>>>(w_kv, ctxth, ctxtl, kvf, 1024, CDIM, NK);
  gemm_mfma_k<<<dim3(NQ / 64, 512 / 64, BB), 256, 0, stream>>>(w_q, qsth, qstl, q3f, 512, CDIM, NQ);
  // 3. fold heads (+L2-normalize q,k)
  fold_k<<<dim3(NQ / 64, 8, BB), 256, 0, stream>>>(q3f, qbuf, 512 * NQ, 0, NQ, 1);
  fold_k<<<dim3(NK / 64, 8, BB), 256, 0, stream>>>(kvf, kbuf, 1024 * NK, 0, NK, 1);
  fold_k<<<dim3(NK / 64, 8, BB), 256, 0, stream>>>(kvf, vbuf, 1024 * NK, 512, NK, 0);
  // 4. split-f16 conversions (q3/kv f32 regions now reusable)
  tof2_k<<<NPQ * 64 / 1024, 256, 0, stream>>>(qbuf, qbh, qbl);
  tof2_k<<<NPK * 64 / 1024, 256, 0, stream>>>(kbuf, kbh, kbl);
  // 5. k-means (init = first 1024 q rows)
  hipMemcpyAsync(cent, qbuf, 65536 * sizeof(float), hipMemcpyDeviceToDevice, stream);
  for (int it = 0; it < 4; ++it) {
    centprep_k<<<1024, 64, 0, stream>>>(cent, csq, cb2h, cb2l);
    hipMemsetAsync(sums, 0, (65536 + 1024) * sizeof(float), stream);
    assign_mfma_k<<<NPQ / 64, 256, 0, stream>>>(qbh, qbl, cb2h, cb2l, csq, asg);
    segsum_k<<<NPQ / 4, 256, 0, stream>>>(qbuf, asg, sums, cnt);
    centup_k<<<65536 / 256, 256, 0, stream>>>(cent, sums, cnt);
  }
  // 6. score keys: argmin (MFMA) -> exact f32 L1 dist -> per-head top-1024
  centprep_k<<<1024, 64, 0, stream>>>(cent, csq, cb2h, cb2l);
  assign_mfma_k<<<NPK / 64, 256, 0, stream>>>(kbh, kbl, cb2h, cb2l, csq, asg);
  dist_k<<<NPK / 4, 256, 0, stream>>>(kbuf, cent, asg, dist);
  topk_k<<<BH, 256, 0, stream>>>(dist, sel);
  // 7. bf16 conversions + gather (kh row-major, vT transposed)
  tobf_k<<<NPQ * 64 / 1024, 256, 0, stream>>>(qbuf, qh);
  gatherb_k<<<dim3(TOPK / 64, BH), 256, 0, stream>>>(kbuf, vbuf, sel, kh, vT);
  // 8. MFMA attention -> split-f16 un-folded [b][n][512]
  attn_mfma_k<<<dim3(NQ / 64, BH), 256, 0, stream>>>(qh, kh, vT, attnth, attntl);
  // 9. output projection (MFMA)
  gemm_mfma_k<<<dim3(NQ / 64, 256 / 64, BB), 256, 0, stream>>>(w_out, attnth, attntl, ybuf, 256, 512, NQ);
  // 10. final LN + residual
  final_k<<<(BB * NQ + 255) / 256, 256, 0, stream>>>(ybuf, on_g, on_b, gamma, qsrc, (float*)d_out);
}

// Round 6
// 1255.895 us; speedup vs baseline: 5.8417x; 1.0001x over previous
//
#include <hip/hip_runtime.h>
#include <math.h>

#define BB 2
#define CDIM 256
#define NQ 4096   // 16*16*16
#define NK 2048   // 8*16*16
#define BH 16
#define TOPK 1024
#define NPQ (BH*NQ)   // 65536
#define NPK (BH*NK)   // 32768

typedef __attribute__((ext_vector_type(8))) short bfx8;
typedef __attribute__((ext_vector_type(8))) _Float16 hfx8;
typedef __attribute__((ext_vector_type(4))) float fx4;
typedef __attribute__((ext_vector_type(4))) unsigned short us4;

__device__ inline unsigned short f2bf(float x) {
  unsigned u = __float_as_uint(x);
  return (unsigned short)((u + 0x7fffu + ((u >> 16) & 1u)) >> 16);
}
__device__ inline unsigned short f2h_bits(float x) {
  _Float16 h = (_Float16)x;
  unsigned short u;
  __builtin_memcpy(&u, &h, 2);
  return u;
}
__device__ inline float h_bits2f(unsigned short u) {
  _Float16 h;
  __builtin_memcpy(&h, &u, 2);
  return (float)h;
}

// ------- channel LayerNorm -> transposed split-f16 [b][n][C] (hi, lo*2048) ---
__global__ void chan_ln_tsplit_k(const float* __restrict__ x, const float* __restrict__ g,
                                 const float* __restrict__ bta,
                                 unsigned short* __restrict__ yh, unsigned short* __restrict__ yl,
                                 int C, int N, int total) {
  int p = blockIdx.x * blockDim.x + threadIdx.x;
  if (p >= total) return;
  int bi = p / N, sp = p - bi * N;
  const float* xb = x + (size_t)bi * C * N + sp;
  float s = 0.f, s2 = 0.f;
  for (int c = 0; c < C; ++c) { float v = xb[(size_t)c * N]; s += v; s2 += v * v; }
  float m = s / C;
  float var = s2 / C - m * m;
  float inv = 1.f / (sqrtf(fmaxf(var, 0.f)) + 1e-6f);
  unsigned short* oh = yh + (size_t)p * C;
  unsigned short* ol = yl + (size_t)p * C;
  for (int c = 0; c < C; c += 4) {
    us4 hh, ll;
#pragma unroll
    for (int j = 0; j < 4; ++j) {
      float v = xb[(size_t)(c + j) * N];
      float ln = g[c + j] * (v - m) * inv + bta[c + j];
      unsigned short hb = f2h_bits(ln);
      hh[j] = hb;
      ll[j] = f2h_bits((ln - h_bits2f(hb)) * 2048.f);
    }
    *(us4*)(oh + c) = hh;
    *(us4*)(ol + c) = ll;
  }
}

// ------- MFMA GEMM: Y[b][o][n] = sum_c W[o][c] * Xt[b][n][c] -----------------
__global__ __launch_bounds__(256) void gemm_mfma_k(
    const float* __restrict__ W, const unsigned short* __restrict__ Xh,
    const unsigned short* __restrict__ Xl, float* __restrict__ Y,
    int O, int C, int N) {
  int t = threadIdx.x, lane = t & 63, wv = t >> 6;
  int lq = lane & 15, lg = lane >> 4;
  int n0 = blockIdx.x * 64, o0 = blockIdx.y * 64 + wv * 16;
  int b = blockIdx.z;
  const unsigned short* xbh = Xh + ((size_t)b * N + n0) * C;
  const unsigned short* xbl = Xl + ((size_t)b * N + n0) * C;
  const float* wr = W + (size_t)(o0 + lq) * C;
  fx4 ahi[4], alo[4];
  for (int nt = 0; nt < 4; ++nt) {
    ahi[nt] = (fx4){0.f, 0.f, 0.f, 0.f};
    alo[nt] = (fx4){0.f, 0.f, 0.f, 0.f};
  }
  for (int k0 = 0; k0 < C; k0 += 32) {
    float4 w0 = *(const float4*)(wr + k0 + lg * 8);
    float4 w1 = *(const float4*)(wr + k0 + lg * 8 + 4);
    float wv8[8] = {w0.x, w0.y, w0.z, w0.w, w1.x, w1.y, w1.z, w1.w};
    hfx8 ah, al;
#pragma unroll
    for (int i = 0; i < 8; ++i) {
      _Float16 h = (_Float16)wv8[i];
      ah[i] = h;
      al[i] = (_Float16)((wv8[i] - (float)h) * 2048.f);
    }
#pragma unroll
    for (int nt = 0; nt < 4; ++nt) {
      const unsigned short* bph = xbh + (size_t)(nt * 16 + lq) * C + k0 + lg * 8;
      const unsigned short* bpl = xbl + (size_t)(nt * 16 + lq) * C + k0 + lg * 8;
      hfx8 bh = *(const hfx8*)bph;
      hfx8 bl = *(const hfx8*)bpl;
      ahi[nt] = __builtin_amdgcn_mfma_f32_16x16x32_f16(ah, bh, ahi[nt], 0, 0, 0);
      alo[nt] = __builtin_amdgcn_mfma_f32_16x16x32_f16(al, bh, alo[nt], 0, 0, 0);
      alo[nt] = __builtin_amdgcn_mfma_f32_16x16x32_f16(ah, bl, alo[nt], 0, 0, 0);
    }
  }
  float* yb = Y + ((size_t)b * O + o0) * N + n0;
#pragma unroll
  for (int nt = 0; nt < 4; ++nt)
#pragma unroll
    for (int r = 0; r < 4; ++r)
      yb[(size_t)(lg * 4 + r) * N + nt * 16 + lq] = ahi[nt][r] + alo[nt][r] * (1.f / 2048.f);
}

// ---------------- fold heads: (b, ch, n) -> (bh, n, 64), optional L2 norm ----
__global__ void fold_k(const float* __restrict__ src, float* __restrict__ dst,
                       int bstride, int choff, int N, int donorm) {
  __shared__ float tile[64 * 65];
  __shared__ float part[4 * 64];
  __shared__ float invn[64];
  int t = threadIdx.x;
  int lane = t & 63, wv = t >> 6;
  int n0 = blockIdx.x * 64;
  int h = blockIdx.y, bi = blockIdx.z;
  const float* sb = src + (size_t)bi * bstride + (size_t)(choff + h * 64) * N + n0;
  for (int r = 0; r < 16; ++r) {
    int d = r * 4 + wv;
    tile[d * 65 + lane] = sb[(size_t)d * N + lane];
  }
  __syncthreads();
  if (donorm) {
    float s = 0.f;
    for (int r = 0; r < 16; ++r) {
      float v = tile[(wv + 4 * r) * 65 + lane];
      s += v * v;
    }
    part[wv * 64 + lane] = s;
    __syncthreads();
    if (t < 64) {
      float tot = part[t] + part[64 + t] + part[128 + t] + part[192 + t];
      invn[t] = 1.f / fmaxf(sqrtf(tot), 1e-12f);
    }
    __syncthreads();
  }
  float* db = dst + ((size_t)(bi * 8 + h) * N + n0) * 64;
  for (int r = 0; r < 16; ++r) {
    int nn = r * 4 + wv;
    float v = tile[lane * 65 + nn];
    if (donorm) v *= invn[nn];
    db[(size_t)nn * 64 + lane] = v;
  }
}

// ---------------- f32 -> split f16 (hi + lo*2048) ----------------------------
__global__ void tof2_k(const float* __restrict__ x, unsigned short* __restrict__ yh,
                       unsigned short* __restrict__ yl) {
  int i = blockIdx.x * 256 + threadIdx.x;
  float4 v = ((const float4*)x)[i];
  us4 h = {f2h_bits(v.x), f2h_bits(v.y), f2h_bits(v.z), f2h_bits(v.w)};
  us4 l = {f2h_bits((v.x - h_bits2f(h.x)) * 2048.f),
           f2h_bits((v.y - h_bits2f(h.y)) * 2048.f),
           f2h_bits((v.z - h_bits2f(h.z)) * 2048.f),
           f2h_bits((v.w - h_bits2f(h.w)) * 2048.f)};
  *(us4*)(yh + (size_t)i * 4) = h;
  *(us4*)(yl + (size_t)i * 4) = l;
}

// ---------------- centroid prep: csq (f32), -2c split f16 --------------------
__global__ void centprep_k(const float* __restrict__ cent, float* __restrict__ csq,
                           unsigned short* __restrict__ cb2h, unsigned short* __restrict__ cb2l) {
  int j = blockIdx.x, lane = threadIdx.x;  // blockDim = 64
  float c = cent[j * 64 + lane];
  float s = c * c;
  for (int off = 32; off; off >>= 1) s += __shfl_xor(s, off);
  if (lane == 0) csq[j] = s;
  float m2 = -2.f * c;
  unsigned short h = f2h_bits(m2);
  cb2h[j * 64 + lane] = h;
  cb2l[j * 64 + lane] = f2h_bits((m2 - h_bits2f(h)) * 2048.f);
}

// ---------------- MFMA nearest-centroid assign (f16 split, reg-pipelined) ----
// Subtile s covers centroids [s*16, (s+1)*16). Depth-2 register prefetch of the
// A-operand (centroid) stream hides L2 latency under MFMA+compare of 2 subtiles.
// Arithmetic per candidate identical to the verified R4 kernel.
__global__ __launch_bounds__(256) void assign_mfma_k(
    const unsigned short* __restrict__ xh, const unsigned short* __restrict__ xl,
    const unsigned short* __restrict__ cb2h, const unsigned short* __restrict__ cb2l,
    const float* __restrict__ csq, int* __restrict__ aout) {
  int t = threadIdx.x, lane = t & 63, wv = t >> 6;
  int lq = lane & 15, lg = lane >> 4;
  int p0 = blockIdx.x * 64 + wv * 16;
  const unsigned short* xb = xh + (size_t)(p0 + lq) * 64;
  const unsigned short* xlb = xl + (size_t)(p0 + lq) * 64;
  hfx8 bh0 = *(const hfx8*)(xb + lg * 8);
  hfx8 bh1 = *(const hfx8*)(xb + 32 + lg * 8);
  hfx8 bl0 = *(const hfx8*)(xlb + lg * 8);
  hfx8 bl1 = *(const hfx8*)(xlb + 32 + lg * 8);
  const size_t aoff = (size_t)lq * 64 + lg * 8;  // row lq, col lg*8 within subtile
  float best = 3.4e38f;
  int bestj = 0;

#define LOADA(S, AH0, AH1, AL0, AL1, CQ)                                 \
  {                                                                      \
    const unsigned short* ar_ = cb2h + (size_t)(S) * 1024 + aoff;        \
    const unsigned short* al_ = cb2l + (size_t)(S) * 1024 + aoff;        \
    AH0 = *(const hfx8*)(ar_);                                           \
    AH1 = *(const hfx8*)(ar_ + 32);                                      \
    AL0 = *(const hfx8*)(al_);                                           \
    AL1 = *(const hfx8*)(al_ + 32);                                      \
    CQ = *(const fx4*)(csq + (S) * 16 + lg * 4);                         \
  }

#define COMPA(S, AH0, AH1, AL0, AL1, CQ)                                 \
  {                                                                      \
    fx4 chi_ = CQ;                                                       \
    chi_ = __builtin_amdgcn_mfma_f32_16x16x32_f16(AH0, bh0, chi_, 0, 0, 0); \
    chi_ = __builtin_amdgcn_mfma_f32_16x16x32_f16(AH1, bh1, chi_, 0, 0, 0); \
    fx4 clo_ = (fx4){0.f, 0.f, 0.f, 0.f};                                \
    clo_ = __builtin_amdgcn_mfma_f32_16x16x32_f16(AH0, bl0, clo_, 0, 0, 0); \
    clo_ = __builtin_amdgcn_mfma_f32_16x16x32_f16(AH1, bl1, clo_, 0, 0, 0); \
    clo_ = __builtin_amdgcn_mfma_f32_16x16x32_f16(AL0, bh0, clo_, 0, 0, 0); \
    clo_ = __builtin_amdgcn_mfma_f32_16x16x32_f16(AL1, bh1, clo_, 0, 0, 0); \
    _Pragma("unroll")                                                    \
    for (int r_ = 0; r_ < 4; ++r_) {                                     \
      int j_ = (S) * 16 + lg * 4 + r_;                                   \
      float d2_ = chi_[r_] + clo_[r_] * (1.f / 2048.f);                  \
      if (d2_ < best) { best = d2_; bestj = j_; }                        \
    }                                                                    \
  }

  hfx8 a0h0, a0h1, a0l0, a0l1;
  hfx8 a1h0, a1h1, a1l0, a1l1;
  fx4 q0v, q1v;
  LOADA(0, a0h0, a0h1, a0l0, a0l1, q0v);
  LOADA(1, a1h0, a1h1, a1l0, a1l1, q1v);
  for (int s = 0; s < 64; s += 2) {
    hfx8 n0h0, n0h1, n0l0, n0l1;
    fx4 nq0;
    LOADA((s + 2) & 63, n0h0, n0h1, n0l0, n0l1, nq0);
    COMPA(s, a0h0, a0h1, a0l0, a0l1, q0v);
    hfx8 n1h0, n1h1, n1l0, n1l1;
    fx4 nq1;
    LOADA((s + 3) & 63, n1h0, n1h1, n1l0, n1l1, nq1);
    COMPA(s + 1, a1h0, a1h1, a1l0, a1l1, q1v);
    a0h0 = n0h0; a0h1 = n0h1; a0l0 = n0l0; a0l1 = n0l1; q0v = nq0;
    a1h0 = n1h0; a1h1 = n1h1; a1l0 = n1l0; a1l1 = n1l1; q1v = nq1;
  }
#undef LOADA
#undef COMPA

  {
    float o = __shfl_xor(best, 16);
    int oj = __shfl_xor(bestj, 16);
    if (o < best || (o == best && oj < bestj)) { best = o; bestj = oj; }
    o = __shfl_xor(best, 32);
    oj = __shfl_xor(bestj, 32);
    if (o < best || (o == best && oj < bestj)) { best = o; bestj = oj; }
  }
  if (lg == 0) aout[p0 + lq] = bestj;
}

// ---------------- exact f32 L1 distance to assigned centroid -----------------
__global__ void dist_k(const float* __restrict__ x, const float* __restrict__ cent,
                       const int* __restrict__ asg, float* __restrict__ dout) {
  int t = threadIdx.x, lane = t & 63, wv = t >> 6;
  int p = blockIdx.x * 4 + wv;
  int a = asg[p];
  float v = fabsf(cent[(size_t)a * 64 + lane] - x[(size_t)p * 64 + lane]);
  for (int off = 32; off; off >>= 1) v += __shfl_xor(v, off);
  if (lane == 0) dout[p] = v;
}

// ---------------- segment sum via atomics ------------------------------------
__global__ void segsum_k(const float* __restrict__ x, const int* __restrict__ asg,
                         float* __restrict__ sums, float* __restrict__ cnt) {
  int t = threadIdx.x, lane = t & 63, wv = t >> 6;
  int p = blockIdx.x * 4 + wv;
  int a = asg[p];
  float v = x[(size_t)p * 64 + lane];
  atomicAdd(&sums[a * 64 + lane], v);
  if (lane == 0) atomicAdd(&cnt[a], 1.0f);
}

// ---------------- centroid update --------------------------------------------
__global__ void centup_k(float* __restrict__ cent, const float* __restrict__ sums,
                         const float* __restrict__ cnt) {
  int i = blockIdx.x * 256 + threadIdx.x;  // 65536 total
  int j = i >> 6;
  float c = cnt[j];
  if (c > 0.f) cent[i] = sums[i] / fmaxf(c, 1.f);
}

// ---------------- per-bh top-1024 by descending dist (stable ties) -----------
__global__ void topk_k(const float* __restrict__ dist, int* __restrict__ sel) {
  __shared__ unsigned long long keys[2048];
  int bh = blockIdx.x, t = threadIdx.x;
  for (int i = t; i < 2048; i += 256) {
    float d = dist[bh * 2048 + i];
    unsigned int db = __float_as_uint(d);  // d >= 0 -> monotonic
    keys[i] = ((unsigned long long)db << 32) | (unsigned int)(2047 - i);
  }
  __syncthreads();
  for (int k = 2; k <= 2048; k <<= 1) {
    for (int j = k >> 1; j > 0; j >>= 1) {
      for (int i = t; i < 2048; i += 256) {
        int ixj = i ^ j;
        if (ixj > i) {
          unsigned long long a = keys[i], b = keys[ixj];
          bool up = ((i & k) == 0);
          bool sw = up ? (a < b) : (a > b);  // descending overall
          if (sw) { keys[i] = b; keys[ixj] = a; }
        }
      }
      __syncthreads();
    }
  }
  for (int i = t; i < 1024; i += 256) {
    sel[bh * 1024 + i] = 2047 - (int)(keys[i] & 0xffffffffu);
  }
}

// ---------------- gather selected rows -> kh (bf16 row-major), vT (bf16 d-major)
__global__ void gatherb_k(const float* __restrict__ kbuf, const float* __restrict__ vbuf,
                          const int* __restrict__ sel, unsigned short* __restrict__ kh,
                          unsigned short* __restrict__ vT) {
  __shared__ unsigned short tile[64][66];
  int t = threadIdx.x, lane = t & 63, wv = t >> 6;
  int bh = blockIdx.y, i0 = blockIdx.x * 64;
  for (int r = 0; r < 16; ++r) {
    int i = r * 4 + wv;
    int src = sel[bh * 1024 + i0 + i];
    float kvv = kbuf[((size_t)bh * 2048 + src) * 64 + lane];
    kh[((size_t)bh * 1024 + i0 + i) * 64 + lane] = f2bf(kvv);
    float vv = vbuf[((size_t)bh * 2048 + src) * 64 + lane];
    tile[i][lane] = f2bf(vv);
  }
  __syncthreads();
  for (int r = 0; r < 16; ++r) {
    int d = r * 4 + wv;
    vT[((size_t)bh * 64 + d) * 1024 + i0 + lane] = tile[lane][d];
  }
}

// ---------------- f32 -> bf16 bulk convert -----------------------------------
__global__ void tobf_k(const float* __restrict__ x, unsigned short* __restrict__ y) {
  int i = blockIdx.x * 256 + threadIdx.x;
  float4 v = ((const float4*)x)[i];
  us4 o = {f2bf(v.x), f2bf(v.y), f2bf(v.z), f2bf(v.w)};
  *(us4*)(y + (size_t)i * 4) = o;
}

// ---------------- MFMA flash attention; out = split-f16 [b][n][h*64+d] ------
__global__ __launch_bounds__(256) void attn_mfma_k(
    const unsigned short* __restrict__ qh, const unsigned short* __restrict__ kh,
    const unsigned short* __restrict__ vT,
    unsigned short* __restrict__ oh, unsigned short* __restrict__ ol) {
  __shared__ unsigned short plds[4][16][72];
  int t = threadIdx.x, lane = t & 63, wv = t >> 6;
  int lq = lane & 15, lg = lane >> 4;
  int bh = blockIdx.y;
  int q0 = blockIdx.x * 64 + wv * 16;
  const unsigned short* qbase = qh + ((size_t)bh * 4096 + q0 + lq) * 64;
  bfx8 qf0 = *(const bfx8*)(qbase + lg * 8);
  bfx8 qf1 = *(const bfx8*)(qbase + 32 + lg * 8);
  fx4 acc[4];
  for (int nt = 0; nt < 4; ++nt) acc[nt] = (fx4){0.f, 0.f, 0.f, 0.f};
  float lsum = 0.f;
  const unsigned short* kbase = kh + (size_t)bh * 1024 * 64;
  const unsigned short* vbase = vT + (size_t)bh * 64 * 1024;
  for (int kt0 = 0; kt0 < 1024; kt0 += 64) {
    fx4 s[4];
    for (int mt = 0; mt < 4; ++mt) {
      const unsigned short* kr = kbase + (size_t)(kt0 + mt * 16 + lq) * 64 + lg * 8;
      bfx8 a0 = *(const bfx8*)(kr);
      bfx8 a1 = *(const bfx8*)(kr + 32);
      fx4 c = (fx4){0.f, 0.f, 0.f, 0.f};
      c = __builtin_amdgcn_mfma_f32_16x16x32_bf16(a0, qf0, c, 0, 0, 0);
      c = __builtin_amdgcn_mfma_f32_16x16x32_bf16(a1, qf1, c, 0, 0, 0);
      s[mt] = c;
    }
    __syncthreads();
    for (int mt = 0; mt < 4; ++mt) {
      float p0 = __expf(s[mt].x), p1 = __expf(s[mt].y);
      float p2 = __expf(s[mt].z), p3 = __expf(s[mt].w);
      lsum += (p0 + p1) + (p2 + p3);
      us4 pk = {f2bf(p0), f2bf(p1), f2bf(p2), f2bf(p3)};
      *(us4*)&plds[wv][lq][mt * 16 + lg * 4] = pk;
    }
    __syncthreads();
    bfx8 pa0 = *(const bfx8*)&plds[wv][lq][lg * 8];
    bfx8 pa1 = *(const bfx8*)&plds[wv][lq][32 + lg * 8];
    for (int nt = 0; nt < 4; ++nt) {
      const unsigned short* vr = vbase + (size_t)(nt * 16 + lq) * 1024 + kt0 + lg * 8;
      bfx8 b0 = *(const bfx8*)(vr);
      bfx8 b1 = *(const bfx8*)(vr + 32);
      acc[nt] = __builtin_amdgcn_mfma_f32_16x16x32_bf16(pa0, b0, acc[nt], 0, 0, 0);
      acc[nt] = __builtin_amdgcn_mfma_f32_16x16x32_bf16(pa1, b1, acc[nt], 0, 0, 0);
    }
  }
  lsum += __shfl_xor(lsum, 16);
  lsum += __shfl_xor(lsum, 32);
  int bi = bh >> 3, hd = bh & 7;
  for (int r = 0; r < 4; ++r) {
    float inv = 1.f / __shfl(lsum, lg * 4 + r);
    size_t rowb = ((size_t)bi * 4096 + q0 + lg * 4 + r) * 512 + hd * 64;
    for (int nt = 0; nt < 4; ++nt) {
      float val = acc[nt][r] * inv;
      unsigned short hb = f2h_bits(val);
      oh[rowb + nt * 16 + lq] = hb;
      ol[rowb + nt * 16 + lq] = f2h_bits((val - h_bits2f(hb)) * 2048.f);
    }
  }
}

// ---------------- final LN + gamma*ln + residual -----------------------------
__global__ void final_k(const float* __restrict__ y, const float* __restrict__ g,
                        const float* __restrict__ bta, const float* __restrict__ gamma,
                        const float* __restrict__ qs, float* __restrict__ out) {
  int p = blockIdx.x * blockDim.x + threadIdx.x;
  if (p >= BB * NQ) return;
  int bi = p >> 12, sp = p & 4095;
  const float* yb = y + (size_t)bi * CDIM * NQ + sp;
  float s = 0.f, s2 = 0.f;
  for (int c = 0; c < CDIM; ++c) { float v = yb[(size_t)c * NQ]; s += v; s2 += v * v; }
  float m = s / CDIM;
  float var = s2 / CDIM - m * m;
  float inv = 1.f / (sqrtf(fmaxf(var, 0.f)) + 1e-6f);
  float gm = gamma[0];
  const float* qb = qs + (size_t)bi * CDIM * NQ + sp;
  float* ob = out + (size_t)bi * CDIM * NQ + sp;
  for (int c = 0; c < CDIM; ++c) {
    float v = yb[(size_t)c * NQ];
    float ln = g[c] * (v - m) * inv + bta[c];
    ob[(size_t)c * NQ] = gm * ln + qb[(size_t)c * NQ];
  }
}

extern "C" void kernel_launch(void* const* d_in, const int* in_sizes, int n_in,
                              void* d_out, int out_size, void* d_ws, size_t ws_size,
                              hipStream_t stream) {
  const float* qsrc = (const float*)d_in[0];
  const float* ctx = (const float*)d_in[1];
  const float* w_q = (const float*)d_in[2];
  const float* w_kv = (const float*)d_in[3];
  const float* w_out = (const float*)d_in[4];
  const float* cn_g = (const float*)d_in[5];
  const float* cn_b = (const float*)d_in[6];
  const float* qn_g = (const float*)d_in[7];
  const float* qn_b = (const float*)d_in[8];
  const float* on_g = (const float*)d_in[9];
  const float* on_b = (const float*)d_in[10];
  const float* gamma = (const float*)d_in[11];

  // scratch layout (floats); total 22,267,904 floats = 89.1 MB
  if (ws_size < (size_t)22267904 * 4) return;
  float* ws = (float*)d_ws;
  float* r_ctx = ws;                      // 1,048,576 f: ctx split-f16; later kh/vT
  float* r_kv = r_ctx + 1048576;          // 4,194,304 f: kv f32; later kbh/kbl; later attnt split
  float* r_qs = r_kv + 4194304;           // 2,097,152 f: qs split-f16; later cb2h/l, ybuf
  float* r_q3 = r_qs + 2097152;           // 4,194,304 f: q3 f32; later qbh/qbl
  float* qbuf = r_q3 + 4194304;           // 4,194,304 f
  float* kbuf = qbuf + 4194304;           // 2,097,152 f
  float* vbuf = kbuf + 2097152;           // 2,097,152 f
  float* cent = vbuf + 2097152;           // 65,536 f
  float* csq = cent + 65536;              // 1,024 f
  float* sums = csq + 1024;               // 65,536 f
  float* cnt = sums + 65536;              // 1,024 f
  int* asg = (int*)(cnt + 1024);          // 65,536 i
  float* dist = (float*)(asg + 65536);    // 32,768 f
  int* sel = (int*)(dist + 32768);        // 16,384 i
  float* kgreg = (float*)(sel + 16384);   // 2,097,152 f (qh bf16)

  unsigned short* ctxth = (unsigned short*)r_ctx;   // [b][2048][256] f16 hi
  unsigned short* ctxtl = ctxth + (size_t)BB * NK * CDIM;  // lo
  unsigned short* qsth = (unsigned short*)r_qs;     // [b][4096][256] f16 hi
  unsigned short* qstl = qsth + (size_t)BB * NQ * CDIM;    // lo
  float* kvf = r_kv;                      // [b][1024][2048] f32
  float* q3f = r_q3;                      // [b][512][4096] f32
  unsigned short* qh = (unsigned short*)kgreg;      // 4M bf16
  unsigned short* kh = (unsigned short*)r_ctx;      // 1M bf16 (ctx split dead)
  unsigned short* vT = kh + 1048576;                // 1M bf16
  unsigned short* qbh = (unsigned short*)r_q3;      // 4M f16 (q split hi)
  unsigned short* qbl = qbh + (size_t)NPQ * 64;     // 4M f16 (lo)
  unsigned short* kbh = (unsigned short*)r_kv;      // 2M f16 (k split hi)
  unsigned short* kbl = kbh + (size_t)NPK * 64;     // 2M f16 (lo)
  unsigned short* cb2h = (unsigned short*)r_qs;     // 64K f16 (-2c hi)
  unsigned short* cb2l = cb2h + 65536;              // 64K f16 (lo)
  unsigned short* attnth = (unsigned short*)r_kv;   // [b][4096][512] f16 hi (kb split dead)
  unsigned short* attntl = attnth + (size_t)BB * NQ * 512;  // lo
  float* ybuf = r_qs;                     // [b][256][4096] f32 (cb2 dead)

  // 1. channel LayerNorms -> transposed split-f16
  chan_ln_tsplit_k<<<(BB * NK + 255) / 256, 256, 0, stream>>>(ctx, cn_g, cn_b, ctxth, ctxtl, CDIM, NK, BB * NK);
  chan_ln_tsplit_k<<<(BB * NQ + 255) / 256, 256, 0, stream>>>(qsrc, qn_g, qn_b, qsth, qstl, CDIM, NQ, BB * NQ);
  // 2. MFMA projections
  gemm_mfma_k<<<dim3(NK / 64, 1024 / 64, BB), 256, 0, stream>>>(w_kv, ctxth, ctxtl, kvf, 1024, CDIM, NK);
  gemm_mfma_k<<<dim3(NQ / 64, 512 / 64, BB), 256, 0, stream>>>(w_q, qsth, qstl, q3f, 512, CDIM, NQ);
  // 3. fold heads (+L2-normalize q,k)
  fold_k<<<dim3(NQ / 64, 8, BB), 256, 0, stream>>>(q3f, qbuf, 512 * NQ, 0, NQ, 1);
  fold_k<<<dim3(NK / 64, 8, BB), 256, 0, stream>>>(kvf, kbuf, 1024 * NK, 0, NK, 1);
  fold_k<<<dim3(NK / 64, 8, BB), 256, 0, stream>>>(kvf, vbuf, 1024 * NK, 512, NK, 0);
  // 4. split-f16 conversions (q3/kv f32 regions now reusable)
  tof2_k<<<NPQ * 64 / 1024, 256, 0, stream>>>(qbuf, qbh, qbl);
  tof2_k<<<NPK * 64 / 1024, 256, 0, stream>>>(kbuf, kbh, kbl);
  // 5. k-means (init = first 1024 q rows)
  hipMemcpyAsync(cent, qbuf, 65536 * sizeof(float), hipMemcpyDeviceToDevice, stream);
  for (int it = 0; it < 4; ++it) {
    centprep_k<<<1024, 64, 0, stream>>>(cent, csq, cb2h, cb2l);
    hipMemsetAsync(sums, 0, (65536 + 1024) * sizeof(float), stream);
    assign_mfma_k<<<NPQ / 64, 256, 0, stream>>>(qbh, qbl, cb2h, cb2l, csq, asg);
    segsum_k<<<NPQ / 4, 256, 0, stream>>>(qbuf, asg, sums, cnt);
    centup_k<<<65536 / 256, 256, 0, stream>>>(cent, sums, cnt);
  }
  // 6. score keys: argmin (MFMA) -> exact f32 L1 dist -> per-head top-1024
  centprep_k<<<1024, 64, 0, stream>>>(cent, csq, cb2h, cb2l);
  assign_mfma_k<<<NPK / 64, 256, 0, stream>>>(kbh, kbl, cb2h, cb2l, csq, asg);
  dist_k<<<NPK / 4, 256, 0, stream>>>(kbuf, cent, asg, dist);
  topk_k<<<BH, 256, 0, stream>>>(dist, sel);
  // 7. bf16 conversions + gather (kh row-major, vT transposed)
  tobf_k<<<NPQ * 64 / 1024, 256, 0, stream>>>(qbuf, qh);
  gatherb_k<<<dim3(TOPK / 64, BH), 256, 0, stream>>>(kbuf, vbuf, sel, kh, vT);
  // 8. MFMA attention -> split-f16 un-folded [b][n][512]
  attn_mfma_k<<<dim3(NQ / 64, BH), 256, 0, stream>>>(qh, kh, vT, attnth, attntl);
  // 9. output projection (MFMA)
  gemm_mfma_k<<<dim3(NQ / 64, 256 / 64, BB), 256, 0, stream>>>(w_out, attnth, attntl, ybuf, 256, 512, NQ);
  // 10. final LN + residual
  final_k<<<(BB * NQ + 255) / 256, 256, 0, stream>>>(ybuf, on_g, on_b, gamma, qsrc, (float*)d_out);
}

// Round 7
// 868.460 us; speedup vs baseline: 8.4478x; 1.4461x over previous
//
#include <hip/hip_runtime.h>
#include <math.h>

#define BB 2
#define CDIM 256
#define NQ 4096   // 16*16*16
#define NK 2048   // 8*16*16
#define BH 16
#define TOPK 1024
#define NPQ (BH*NQ)   // 65536
#define NPK (BH*NK)   // 32768

typedef __attribute__((ext_vector_type(8))) short bfx8;
typedef __attribute__((ext_vector_type(8))) _Float16 hfx8;
typedef __attribute__((ext_vector_type(4))) float fx4;
typedef __attribute__((ext_vector_type(4))) unsigned short us4;

__device__ inline unsigned short f2bf(float x) {
  unsigned u = __float_as_uint(x);
  return (unsigned short)((u + 0x7fffu + ((u >> 16) & 1u)) >> 16);
}
__device__ inline unsigned short f2h_bits(float x) {
  _Float16 h = (_Float16)x;
  unsigned short u;
  __builtin_memcpy(&u, &h, 2);
  return u;
}
__device__ inline float h_bits2f(unsigned short u) {
  _Float16 h;
  __builtin_memcpy(&h, &u, 2);
  return (float)h;
}

// ------- channel LayerNorm -> transposed split-f16 [b][n][C] (hi, lo*2048) ---
__global__ void chan_ln_tsplit_k(const float* __restrict__ x, const float* __restrict__ g,
                                 const float* __restrict__ bta,
                                 unsigned short* __restrict__ yh, unsigned short* __restrict__ yl,
                                 int C, int N, int total) {
  int p = blockIdx.x * blockDim.x + threadIdx.x;
  if (p >= total) return;
  int bi = p / N, sp = p - bi * N;
  const float* xb = x + (size_t)bi * C * N + sp;
  float s = 0.f, s2 = 0.f;
  for (int c = 0; c < C; ++c) { float v = xb[(size_t)c * N]; s += v; s2 += v * v; }
  float m = s / C;
  float var = s2 / C - m * m;
  float inv = 1.f / (sqrtf(fmaxf(var, 0.f)) + 1e-6f);
  unsigned short* oh = yh + (size_t)p * C;
  unsigned short* ol = yl + (size_t)p * C;
  for (int c = 0; c < C; c += 4) {
    us4 hh, ll;
#pragma unroll
    for (int j = 0; j < 4; ++j) {
      float v = xb[(size_t)(c + j) * N];
      float ln = g[c + j] * (v - m) * inv + bta[c + j];
      unsigned short hb = f2h_bits(ln);
      hh[j] = hb;
      ll[j] = f2h_bits((ln - h_bits2f(hb)) * 2048.f);
    }
    *(us4*)(oh + c) = hh;
    *(us4*)(ol + c) = ll;
  }
}

// ------- MFMA GEMM: Y[b][o][n] = sum_c W[o][c] * Xt[b][n][c] -----------------
__global__ __launch_bounds__(256) void gemm_mfma_k(
    const float* __restrict__ W, const unsigned short* __restrict__ Xh,
    const unsigned short* __restrict__ Xl, float* __restrict__ Y,
    int O, int C, int N) {
  int t = threadIdx.x, lane = t & 63, wv = t >> 6;
  int lq = lane & 15, lg = lane >> 4;
  int n0 = blockIdx.x * 64, o0 = blockIdx.y * 64 + wv * 16;
  int b = blockIdx.z;
  const unsigned short* xbh = Xh + ((size_t)b * N + n0) * C;
  const unsigned short* xbl = Xl + ((size_t)b * N + n0) * C;
  const float* wr = W + (size_t)(o0 + lq) * C;
  fx4 ahi[4], alo[4];
  for (int nt = 0; nt < 4; ++nt) {
    ahi[nt] = (fx4){0.f, 0.f, 0.f, 0.f};
    alo[nt] = (fx4){0.f, 0.f, 0.f, 0.f};
  }
  for (int k0 = 0; k0 < C; k0 += 32) {
    float4 w0 = *(const float4*)(wr + k0 + lg * 8);
    float4 w1 = *(const float4*)(wr + k0 + lg * 8 + 4);
    float wv8[8] = {w0.x, w0.y, w0.z, w0.w, w1.x, w1.y, w1.z, w1.w};
    hfx8 ah, al;
#pragma unroll
    for (int i = 0; i < 8; ++i) {
      _Float16 h = (_Float16)wv8[i];
      ah[i] = h;
      al[i] = (_Float16)((wv8[i] - (float)h) * 2048.f);
    }
#pragma unroll
    for (int nt = 0; nt < 4; ++nt) {
      const unsigned short* bph = xbh + (size_t)(nt * 16 + lq) * C + k0 + lg * 8;
      const unsigned short* bpl = xbl + (size_t)(nt * 16 + lq) * C + k0 + lg * 8;
      hfx8 bh = *(const hfx8*)bph;
      hfx8 bl = *(const hfx8*)bpl;
      ahi[nt] = __builtin_amdgcn_mfma_f32_16x16x32_f16(ah, bh, ahi[nt], 0, 0, 0);
      alo[nt] = __builtin_amdgcn_mfma_f32_16x16x32_f16(al, bh, alo[nt], 0, 0, 0);
      alo[nt] = __builtin_amdgcn_mfma_f32_16x16x32_f16(ah, bl, alo[nt], 0, 0, 0);
    }
  }
  float* yb = Y + ((size_t)b * O + o0) * N + n0;
#pragma unroll
  for (int nt = 0; nt < 4; ++nt)
#pragma unroll
    for (int r = 0; r < 4; ++r)
      yb[(size_t)(lg * 4 + r) * N + nt * 16 + lq] = ahi[nt][r] + alo[nt][r] * (1.f / 2048.f);
}

// ---------------- fold heads: (b, ch, n) -> (bh, n, 64), optional L2 norm ----
__global__ void fold_k(const float* __restrict__ src, float* __restrict__ dst,
                       int bstride, int choff, int N, int donorm) {
  __shared__ float tile[64 * 65];
  __shared__ float part[4 * 64];
  __shared__ float invn[64];
  int t = threadIdx.x;
  int lane = t & 63, wv = t >> 6;
  int n0 = blockIdx.x * 64;
  int h = blockIdx.y, bi = blockIdx.z;
  const float* sb = src + (size_t)bi * bstride + (size_t)(choff + h * 64) * N + n0;
  for (int r = 0; r < 16; ++r) {
    int d = r * 4 + wv;
    tile[d * 65 + lane] = sb[(size_t)d * N + lane];
  }
  __syncthreads();
  if (donorm) {
    float s = 0.f;
    for (int r = 0; r < 16; ++r) {
      float v = tile[(wv + 4 * r) * 65 + lane];
      s += v * v;
    }
    part[wv * 64 + lane] = s;
    __syncthreads();
    if (t < 64) {
      float tot = part[t] + part[64 + t] + part[128 + t] + part[192 + t];
      invn[t] = 1.f / fmaxf(sqrtf(tot), 1e-12f);
    }
    __syncthreads();
  }
  float* db = dst + ((size_t)(bi * 8 + h) * N + n0) * 64;
  for (int r = 0; r < 16; ++r) {
    int nn = r * 4 + wv;
    float v = tile[lane * 65 + nn];
    if (donorm) v *= invn[nn];
    db[(size_t)nn * 64 + lane] = v;
  }
}

// ---------------- f32 -> split f16 (hi + lo*2048) ----------------------------
__global__ void tof2_k(const float* __restrict__ x, unsigned short* __restrict__ yh,
                       unsigned short* __restrict__ yl) {
  int i = blockIdx.x * 256 + threadIdx.x;
  float4 v = ((const float4*)x)[i];
  us4 h = {f2h_bits(v.x), f2h_bits(v.y), f2h_bits(v.z), f2h_bits(v.w)};
  us4 l = {f2h_bits((v.x - h_bits2f(h.x)) * 2048.f),
           f2h_bits((v.y - h_bits2f(h.y)) * 2048.f),
           f2h_bits((v.z - h_bits2f(h.z)) * 2048.f),
           f2h_bits((v.w - h_bits2f(h.w)) * 2048.f)};
  *(us4*)(yh + (size_t)i * 4) = h;
  *(us4*)(yl + (size_t)i * 4) = l;
}

// ---------------- centroid prep: csq (f32), -2c split f16 --------------------
__global__ void centprep_k(const float* __restrict__ cent, float* __restrict__ csq,
                           unsigned short* __restrict__ cb2h, unsigned short* __restrict__ cb2l) {
  int j = blockIdx.x, lane = threadIdx.x;  // blockDim = 64
  float c = cent[j * 64 + lane];
  float s = c * c;
  for (int off = 32; off; off >>= 1) s += __shfl_xor(s, off);
  if (lane == 0) csq[j] = s;
  float m2 = -2.f * c;
  unsigned short h = f2h_bits(m2);
  cb2h[j * 64 + lane] = h;
  cb2l[j * 64 + lane] = f2h_bits((m2 - h_bits2f(h)) * 2048.f);
}

// ---------------- MFMA nearest-centroid assign (f16 split, LDS-staged) -------
// Subtile s = centroids [s*16,(s+1)*16). Block stages each subtile (hi+lo, 4KB)
// into LDS once (reg-staged, XOR-swizzled rows), double-buffered; all 4 waves
// read A-fragments via ds_read_b128. Arithmetic identical to verified R4.
__global__ __launch_bounds__(256) void assign_mfma_k(
    const unsigned short* __restrict__ xh, const unsigned short* __restrict__ xl,
    const unsigned short* __restrict__ cb2h, const unsigned short* __restrict__ cb2l,
    const float* __restrict__ csq, int* __restrict__ aout) {
  __shared__ __align__(16) unsigned short clds[2][2][1024];  // [buf][hi/lo][16x64]
  int t = threadIdx.x, lane = t & 63, wv = t >> 6;
  int lq = lane & 15, lg = lane >> 4;
  int p0 = blockIdx.x * 64 + wv * 16;
  const unsigned short* xb = xh + (size_t)(p0 + lq) * 64;
  const unsigned short* xlb = xl + (size_t)(p0 + lq) * 64;
  hfx8 bh0 = *(const hfx8*)(xb + lg * 8);
  hfx8 bh1 = *(const hfx8*)(xb + 32 + lg * 8);
  hfx8 bl0 = *(const hfx8*)(xlb + lg * 8);
  hfx8 bl1 = *(const hfx8*)(xlb + 32 + lg * 8);

  // staging role: threads 0-127 stage hi part, 128-255 stage lo part (16B each)
  int part = t >> 7;
  int abyte = (t & 127) * 16;                       // linear byte in 2KB subtile
  int wbyte = abyte ^ (((abyte >> 7) & 7) << 4);    // XOR-swizzled dest
  const unsigned short* gsrc = (part ? cb2l : cb2h) + (abyte >> 1);
  // read addresses (same swizzle)
  int rowoff = lq * 128;
  int x0 = (lg * 16) ^ ((lq & 7) << 4);
  int x1 = (64 + lg * 16) ^ ((lq & 7) << 4);

  float best = 3.4e38f;
  int bestj = 0;

  // prologue: stage subtile 0 into buf 0
  uint4 r0 = *(const uint4*)(gsrc);
  *(uint4*)((char*)&clds[0][part][0] + wbyte) = r0;

  for (int s = 0; s < 64; ++s) {
    int cur = s & 1;
    __syncthreads();  // staged writes for s visible; all reads of buf cur^1 done
    uint4 rn;
    if (s < 63) rn = *(const uint4*)(gsrc + (size_t)(s + 1) * 1024);
    __builtin_amdgcn_sched_barrier(0);  // keep prefetch issue above compute
    const char* ph = (const char*)&clds[cur][0][0];
    const char* pl = (const char*)&clds[cur][1][0];
    hfx8 ah0 = *(const hfx8*)(ph + rowoff + x0);
    hfx8 ah1 = *(const hfx8*)(ph + rowoff + x1);
    hfx8 al0 = *(const hfx8*)(pl + rowoff + x0);
    hfx8 al1 = *(const hfx8*)(pl + rowoff + x1);
    fx4 chi = *(const fx4*)(csq + s * 16 + lg * 4);
    chi = __builtin_amdgcn_mfma_f32_16x16x32_f16(ah0, bh0, chi, 0, 0, 0);
    chi = __builtin_amdgcn_mfma_f32_16x16x32_f16(ah1, bh1, chi, 0, 0, 0);
    fx4 clo = (fx4){0.f, 0.f, 0.f, 0.f};
    clo = __builtin_amdgcn_mfma_f32_16x16x32_f16(ah0, bl0, clo, 0, 0, 0);
    clo = __builtin_amdgcn_mfma_f32_16x16x32_f16(ah1, bl1, clo, 0, 0, 0);
    clo = __builtin_amdgcn_mfma_f32_16x16x32_f16(al0, bh0, clo, 0, 0, 0);
    clo = __builtin_amdgcn_mfma_f32_16x16x32_f16(al1, bh1, clo, 0, 0, 0);
#pragma unroll
    for (int r_ = 0; r_ < 4; ++r_) {
      int j_ = s * 16 + lg * 4 + r_;
      float d2_ = chi[r_] + clo[r_] * (1.f / 2048.f);
      if (d2_ < best) { best = d2_; bestj = j_; }
    }
    __builtin_amdgcn_sched_barrier(0);  // keep ds_write below compute
    if (s < 63) *(uint4*)((char*)&clds[cur ^ 1][part][0] + wbyte) = rn;
  }

  // merge across lg groups (lanes lq, lq+16, lq+32, lq+48); tie -> lower j
  {
    float o = __shfl_xor(best, 16);
    int oj = __shfl_xor(bestj, 16);
    if (o < best || (o == best && oj < bestj)) { best = o; bestj = oj; }
    o = __shfl_xor(best, 32);
    oj = __shfl_xor(bestj, 32);
    if (o < best || (o == best && oj < bestj)) { best = o; bestj = oj; }
  }
  if (lg == 0) aout[p0 + lq] = bestj;
}

// ---------------- exact f32 L1 distance to assigned centroid -----------------
__global__ void dist_k(const float* __restrict__ x, const float* __restrict__ cent,
                       const int* __restrict__ asg, float* __restrict__ dout) {
  int t = threadIdx.x, lane = t & 63, wv = t >> 6;
  int p = blockIdx.x * 4 + wv;
  int a = asg[p];
  float v = fabsf(cent[(size_t)a * 64 + lane] - x[(size_t)p * 64 + lane]);
  for (int off = 32; off; off >>= 1) v += __shfl_xor(v, off);
  if (lane == 0) dout[p] = v;
}

// ---------------- segment sum via atomics ------------------------------------
__global__ void segsum_k(const float* __restrict__ x, const int* __restrict__ asg,
                         float* __restrict__ sums, float* __restrict__ cnt) {
  int t = threadIdx.x, lane = t & 63, wv = t >> 6;
  int p = blockIdx.x * 4 + wv;
  int a = asg[p];
  float v = x[(size_t)p * 64 + lane];
  atomicAdd(&sums[a * 64 + lane], v);
  if (lane == 0) atomicAdd(&cnt[a], 1.0f);
}

// ---------------- centroid update --------------------------------------------
__global__ void centup_k(float* __restrict__ cent, const float* __restrict__ sums,
                         const float* __restrict__ cnt) {
  int i = blockIdx.x * 256 + threadIdx.x;  // 65536 total
  int j = i >> 6;
  float c = cnt[j];
  if (c > 0.f) cent[i] = sums[i] / fmaxf(c, 1.f);
}

// ---------------- per-bh top-1024 by descending dist (stable ties) -----------
__global__ void topk_k(const float* __restrict__ dist, int* __restrict__ sel) {
  __shared__ unsigned long long keys[2048];
  int bh = blockIdx.x, t = threadIdx.x;
  for (int i = t; i < 2048; i += 256) {
    float d = dist[bh * 2048 + i];
    unsigned int db = __float_as_uint(d);  // d >= 0 -> monotonic
    keys[i] = ((unsigned long long)db << 32) | (unsigned int)(2047 - i);
  }
  __syncthreads();
  for (int k = 2; k <= 2048; k <<= 1) {
    for (int j = k >> 1; j > 0; j >>= 1) {
      for (int i = t; i < 2048; i += 256) {
        int ixj = i ^ j;
        if (ixj > i) {
          unsigned long long a = keys[i], b = keys[ixj];
          bool up = ((i & k) == 0);
          bool sw = up ? (a < b) : (a > b);  // descending overall
          if (sw) { keys[i] = b; keys[ixj] = a; }
        }
      }
      __syncthreads();
    }
  }
  for (int i = t; i < 1024; i += 256) {
    sel[bh * 1024 + i] = 2047 - (int)(keys[i] & 0xffffffffu);
  }
}

// ---------------- gather selected rows -> kh (bf16 row-major), vT (bf16 d-major)
__global__ void gatherb_k(const float* __restrict__ kbuf, const float* __restrict__ vbuf,
                          const int* __restrict__ sel, unsigned short* __restrict__ kh,
                          unsigned short* __restrict__ vT) {
  __shared__ unsigned short tile[64][66];
  int t = threadIdx.x, lane = t & 63, wv = t >> 6;
  int bh = blockIdx.y, i0 = blockIdx.x * 64;
  for (int r = 0; r < 16; ++r) {
    int i = r * 4 + wv;
    int src = sel[bh * 1024 + i0 + i];
    float kvv = kbuf[((size_t)bh * 2048 + src) * 64 + lane];
    kh[((size_t)bh * 1024 + i0 + i) * 64 + lane] = f2bf(kvv);
    float vv = vbuf[((size_t)bh * 2048 + src) * 64 + lane];
    tile[i][lane] = f2bf(vv);
  }
  __syncthreads();
  for (int r = 0; r < 16; ++r) {
    int d = r * 4 + wv;
    vT[((size_t)bh * 64 + d) * 1024 + i0 + lane] = tile[lane][d];
  }
}

// ---------------- f32 -> bf16 bulk convert -----------------------------------
__global__ void tobf_k(const float* __restrict__ x, unsigned short* __restrict__ y) {
  int i = blockIdx.x * 256 + threadIdx.x;
  float4 v = ((const float4*)x)[i];
  us4 o = {f2bf(v.x), f2bf(v.y), f2bf(v.z), f2bf(v.w)};
  *(us4*)(y + (size_t)i * 4) = o;
}

// ---------------- MFMA flash attention; out = split-f16 [b][n][h*64+d] ------
__global__ __launch_bounds__(256) void attn_mfma_k(
    const unsigned short* __restrict__ qh, const unsigned short* __restrict__ kh,
    const unsigned short* __restrict__ vT,
    unsigned short* __restrict__ oh, unsigned short* __restrict__ ol) {
  __shared__ unsigned short plds[4][16][72];
  int t = threadIdx.x, lane = t & 63, wv = t >> 6;
  int lq = lane & 15, lg = lane >> 4;
  int bh = blockIdx.y;
  int q0 = blockIdx.x * 64 + wv * 16;
  const unsigned short* qbase = qh + ((size_t)bh * 4096 + q0 + lq) * 64;
  bfx8 qf0 = *(const bfx8*)(qbase + lg * 8);
  bfx8 qf1 = *(const bfx8*)(qbase + 32 + lg * 8);
  fx4 acc[4];
  for (int nt = 0; nt < 4; ++nt) acc[nt] = (fx4){0.f, 0.f, 0.f, 0.f};
  float lsum = 0.f;
  const unsigned short* kbase = kh + (size_t)bh * 1024 * 64;
  const unsigned short* vbase = vT + (size_t)bh * 64 * 1024;
  for (int kt0 = 0; kt0 < 1024; kt0 += 64) {
    fx4 s[4];
    for (int mt = 0; mt < 4; ++mt) {
      const unsigned short* kr = kbase + (size_t)(kt0 + mt * 16 + lq) * 64 + lg * 8;
      bfx8 a0 = *(const bfx8*)(kr);
      bfx8 a1 = *(const bfx8*)(kr + 32);
      fx4 c = (fx4){0.f, 0.f, 0.f, 0.f};
      c = __builtin_amdgcn_mfma_f32_16x16x32_bf16(a0, qf0, c, 0, 0, 0);
      c = __builtin_amdgcn_mfma_f32_16x16x32_bf16(a1, qf1, c, 0, 0, 0);
      s[mt] = c;
    }
    __syncthreads();
    for (int mt = 0; mt < 4; ++mt) {
      float p0 = __expf(s[mt].x), p1 = __expf(s[mt].y);
      float p2 = __expf(s[mt].z), p3 = __expf(s[mt].w);
      lsum += (p0 + p1) + (p2 + p3);
      us4 pk = {f2bf(p0), f2bf(p1), f2bf(p2), f2bf(p3)};
      *(us4*)&plds[wv][lq][mt * 16 + lg * 4] = pk;
    }
    __syncthreads();
    bfx8 pa0 = *(const bfx8*)&plds[wv][lq][lg * 8];
    bfx8 pa1 = *(const bfx8*)&plds[wv][lq][32 + lg * 8];
    for (int nt = 0; nt < 4; ++nt) {
      const unsigned short* vr = vbase + (size_t)(nt * 16 + lq) * 1024 + kt0 + lg * 8;
      bfx8 b0 = *(const bfx8*)(vr);
      bfx8 b1 = *(const bfx8*)(vr + 32);
      acc[nt] = __builtin_amdgcn_mfma_f32_16x16x32_bf16(pa0, b0, acc[nt], 0, 0, 0);
      acc[nt] = __builtin_amdgcn_mfma_f32_16x16x32_bf16(pa1, b1, acc[nt], 0, 0, 0);
    }
  }
  lsum += __shfl_xor(lsum, 16);
  lsum += __shfl_xor(lsum, 32);
  int bi = bh >> 3, hd = bh & 7;
  for (int r = 0; r < 4; ++r) {
    float inv = 1.f / __shfl(lsum, lg * 4 + r);
    size_t rowb = ((size_t)bi * 4096 + q0 + lg * 4 + r) * 512 + hd * 64;
    for (int nt = 0; nt < 4; ++nt) {
      float val = acc[nt][r] * inv;
      unsigned short hb = f2h_bits(val);
      oh[rowb + nt * 16 + lq] = hb;
      ol[rowb + nt * 16 + lq] = f2h_bits((val - h_bits2f(hb)) * 2048.f);
    }
  }
}

// ---------------- final LN + gamma*ln + residual -----------------------------
__global__ void final_k(const float* __restrict__ y, const float* __restrict__ g,
                        const float* __restrict__ bta, const float* __restrict__ gamma,
                        const float* __restrict__ qs, float* __restrict__ out) {
  int p = blockIdx.x * blockDim.x + threadIdx.x;
  if (p >= BB * NQ) return;
  int bi = p >> 12, sp = p & 4095;
  const float* yb = y + (size_t)bi * CDIM * NQ + sp;
  float s = 0.f, s2 = 0.f;
  for (int c = 0; c < CDIM; ++c) { float v = yb[(size_t)c * NQ]; s += v; s2 += v * v; }
  float m = s / CDIM;
  float var = s2 / CDIM - m * m;
  float inv = 1.f / (sqrtf(fmaxf(var, 0.f)) + 1e-6f);
  float gm = gamma[0];
  const float* qb = qs + (size_t)bi * CDIM * NQ + sp;
  float* ob = out + (size_t)bi * CDIM * NQ + sp;
  for (int c = 0; c < CDIM; ++c) {
    float v = yb[(size_t)c * NQ];
    float ln = g[c] * (v - m) * inv + bta[c];
    ob[(size_t)c * NQ] = gm * ln + qb[(size_t)c * NQ];
  }
}

extern "C" void kernel_launch(void* const* d_in, const int* in_sizes, int n_in,
                              void* d_out, int out_size, void* d_ws, size_t ws_size,
                              hipStream_t stream) {
  const float* qsrc = (const float*)d_in[0];
  const float* ctx = (const float*)d_in[1];
  const float* w_q = (const float*)d_in[2];
  const float* w_kv = (const float*)d_in[3];
  const float* w_out = (const float*)d_in[4];
  const float* cn_g = (const float*)d_in[5];
  const float* cn_b = (const float*)d_in[6];
  const float* qn_g = (const float*)d_in[7];
  const float* qn_b = (const float*)d_in[8];
  const float* on_g = (const float*)d_in[9];
  const float* on_b = (const float*)d_in[10];
  const float* gamma = (const float*)d_in[11];

  // scratch layout (floats); total 22,267,904 floats = 89.1 MB
  if (ws_size < (size_t)22267904 * 4) return;
  float* ws = (float*)d_ws;
  float* r_ctx = ws;                      // 1,048,576 f: ctx split-f16; later kh/vT
  float* r_kv = r_ctx + 1048576;          // 4,194,304 f: kv f32; later kbh/kbl; later attnt split
  float* r_qs = r_kv + 4194304;           // 2,097,152 f: qs split-f16; later cb2h/l, ybuf
  float* r_q3 = r_qs + 2097152;           // 4,194,304 f: q3 f32; later qbh/qbl
  float* qbuf = r_q3 + 4194304;           // 4,194,304 f
  float* kbuf = qbuf + 4194304;           // 2,097,152 f
  float* vbuf = kbuf + 2097152;           // 2,097,152 f
  float* cent = vbuf + 2097152;           // 65,536 f
  float* csq = cent + 65536;              // 1,024 f
  float* sums = csq + 1024;               // 65,536 f
  float* cnt = sums + 65536;              // 1,024 f
  int* asg = (int*)(cnt + 1024);          // 65,536 i
  float* dist = (float*)(asg + 65536);    // 32,768 f
  int* sel = (int*)(dist + 32768);        // 16,384 i
  float* kgreg = (float*)(sel + 16384);   // 2,097,152 f (qh bf16)

  unsigned short* ctxth = (unsigned short*)r_ctx;   // [b][2048][256] f16 hi
  unsigned short* ctxtl = ctxth + (size_t)BB * NK * CDIM;  // lo
  unsigned short* qsth = (unsigned short*)r_qs;     // [b][4096][256] f16 hi
  unsigned short* qstl = qsth + (size_t)BB * NQ * CDIM;    // lo
  float* kvf = r_kv;                      // [b][1024][2048] f32
  float* q3f = r_q3;                      // [b][512][4096] f32
  unsigned short* qh = (unsigned short*)kgreg;      // 4M bf16
  unsigned short* kh = (unsigned short*)r_ctx;      // 1M bf16 (ctx split dead)
  unsigned short* vT = kh + 1048576;                // 1M bf16
  unsigned short* qbh = (unsigned short*)r_q3;      // 4M f16 (q split hi)
  unsigned short* qbl = qbh + (size_t)NPQ * 64;     // 4M f16 (lo)
  unsigned short* kbh = (unsigned short*)r_kv;      // 2M f16 (k split hi)
  unsigned short* kbl = kbh + (size_t)NPK * 64;     // 2M f16 (lo)
  unsigned short* cb2h = (unsigned short*)r_qs;     // 64K f16 (-2c hi)
  unsigned short* cb2l = cb2h + 65536;              // 64K f16 (lo)
  unsigned short* attnth = (unsigned short*)r_kv;   // [b][4096][512] f16 hi (kb split dead)
  unsigned short* attntl = attnth + (size_t)BB * NQ * 512;  // lo
  float* ybuf = r_qs;                     // [b][256][4096] f32 (cb2 dead)

  // 1. channel LayerNorms -> transposed split-f16
  chan_ln_tsplit_k<<<(BB * NK + 255) / 256, 256, 0, stream>>>(ctx, cn_g, cn_b, ctxth, ctxtl, CDIM, NK, BB * NK);
  chan_ln_tsplit_k<<<(BB * NQ + 255) / 256, 256, 0, stream>>>(qsrc, qn_g, qn_b, qsth, qstl, CDIM, NQ, BB * NQ);
  // 2. MFMA projections
  gemm_mfma_k<<<dim3(NK / 64, 1024 / 64, BB), 256, 0, stream>>>(w_kv, ctxth, ctxtl, kvf, 1024, CDIM, NK);
  gemm_mfma_k<<<dim3(NQ / 64, 512 / 64, BB), 256, 0, stream>>>(w_q, qsth, qstl, q3f, 512, CDIM, NQ);
  // 3. fold heads (+L2-normalize q,k)
  fold_k<<<dim3(NQ / 64, 8, BB), 256, 0, stream>>>(q3f, qbuf, 512 * NQ, 0, NQ, 1);
  fold_k<<<dim3(NK / 64, 8, BB), 256, 0, stream>>>(kvf, kbuf, 1024 * NK, 0, NK, 1);
  fold_k<<<dim3(NK / 64, 8, BB), 256, 0, stream>>>(kvf, vbuf, 1024 * NK, 512, NK, 0);
  // 4. split-f16 conversions (q3/kv f32 regions now reusable)
  tof2_k<<<NPQ * 64 / 1024, 256, 0, stream>>>(qbuf, qbh, qbl);
  tof2_k<<<NPK * 64 / 1024, 256, 0, stream>>>(kbuf, kbh, kbl);
  // 5. k-means (init = first 1024 q rows)
  hipMemcpyAsync(cent, qbuf, 65536 * sizeof(float), hipMemcpyDeviceToDevice, stream);
  for (int it = 0; it < 4; ++it) {
    centprep_k<<<1024, 64, 0, stream>>>(cent, csq, cb2h, cb2l);
    hipMemsetAsync(sums, 0, (65536 + 1024) * sizeof(float), stream);
    assign_mfma_k<<<NPQ / 64, 256, 0, stream>>>(qbh, qbl, cb2h, cb2l, csq, asg);
    segsum_k<<<NPQ / 4, 256, 0, stream>>>(qbuf, asg, sums, cnt);
    centup_k<<<65536 / 256, 256, 0, stream>>>(cent, sums, cnt);
  }
  // 6. score keys: argmin (MFMA) -> exact f32 L1 dist -> per-head top-1024
  centprep_k<<<1024, 64, 0, stream>>>(cent, csq, cb2h, cb2l);
  assign_mfma_k<<<NPK / 64, 256, 0, stream>>>(kbh, kbl, cb2h, cb2l, csq, asg);
  dist_k<<<NPK / 4, 256, 0, stream>>>(kbuf, cent, asg, dist);
  topk_k<<<BH, 256, 0, stream>>>(dist, sel);
  // 7. bf16 conversions + gather (kh row-major, vT transposed)
  tobf_k<<<NPQ * 64 / 1024, 256, 0, stream>>>(qbuf, qh);
  gatherb_k<<<dim3(TOPK / 64, BH), 256, 0, stream>>>(kbuf, vbuf, sel, kh, vT);
  // 8. MFMA attention -> split-f16 un-folded [b][n][512]
  attn_mfma_k<<<dim3(NQ / 64, BH), 256, 0, stream>>>(qh, kh, vT, attnth, attntl);
  // 9. output projection (MFMA)
  gemm_mfma_k<<<dim3(NQ / 64, 256 / 64, BB), 256, 0, stream>>>(w_out, attnth, attntl, ybuf, 256, 512, NQ);
  // 10. final LN + residual
  final_k<<<(BB * NQ + 255) / 256, 256, 0, stream>>>(ybuf, on_g, on_b, gamma, qsrc, (float*)d_out);
}

// Round 8
// 659.171 us; speedup vs baseline: 11.1301x; 1.3175x over previous
//
#include <hip/hip_runtime.h>
#include <math.h>

#define BB 2
#define CDIM 256
#define NQ 4096   // 16*16*16
#define NK 2048   // 8*16*16
#define BH 16
#define TOPK 1024
#define NPQ (BH*NQ)   // 65536
#define NPK (BH*NK)   // 32768

typedef __attribute__((ext_vector_type(8))) short bfx8;
typedef __attribute__((ext_vector_type(8))) _Float16 hfx8;
typedef __attribute__((ext_vector_type(4))) float fx4;
typedef __attribute__((ext_vector_type(4))) unsigned short us4;

__device__ inline unsigned short f2bf(float x) {
  unsigned u = __float_as_uint(x);
  return (unsigned short)((u + 0x7fffu + ((u >> 16) & 1u)) >> 16);
}
__device__ inline unsigned short f2h_bits(float x) {
  _Float16 h = (_Float16)x;
  unsigned short u;
  __builtin_memcpy(&u, &h, 2);
  return u;
}
__device__ inline float h_bits2f(unsigned short u) {
  _Float16 h;
  __builtin_memcpy(&h, &u, 2);
  return (float)h;
}

// ------- channel LayerNorm -> transposed split-f16 [b][n][C] (hi, lo*2048) ---
// block = 4 waves over 64 positions; wave w covers channels [w*64, w*64+64).
__global__ __launch_bounds__(256) void chan_ln_tsplit_k(
    const float* __restrict__ x, const float* __restrict__ g,
    const float* __restrict__ bta, unsigned short* __restrict__ yh,
    unsigned short* __restrict__ yl, int C, int N) {
  __shared__ float tile[4][64][65];
  __shared__ float p1[4][64], p2[4][64];
  __shared__ float mArr[64], invArr[64];
  int t = threadIdx.x, lane = t & 63, wv = t >> 6;
  int n0 = blockIdx.x * 64, bi = blockIdx.y;
  const float* xb = x + (size_t)bi * C * N + n0 + lane;
  float s = 0.f, s2 = 0.f;
  for (int cl = 0; cl < 64; ++cl) {
    float v = xb[(size_t)(wv * 64 + cl) * N];
    tile[wv][cl][lane] = v;
    s += v;
    s2 += v * v;
  }
  p1[wv][lane] = s;
  p2[wv][lane] = s2;
  __syncthreads();
  if (t < 64) {
    float ts = p1[0][t] + p1[1][t] + p1[2][t] + p1[3][t];
    float ts2 = p2[0][t] + p2[1][t] + p2[2][t] + p2[3][t];
    float m = ts / C;
    float var = ts2 / C - m * m;
    mArr[t] = m;
    invArr[t] = 1.f / (sqrtf(fmaxf(var, 0.f)) + 1e-6f);
  }
  __syncthreads();
  int c = wv * 64 + lane;  // lane = channel in phase 2
  float gc = g[c], bc = bta[c];
  unsigned short* ohb = yh + ((size_t)bi * N + n0) * C + c;
  unsigned short* olb = yl + ((size_t)bi * N + n0) * C + c;
  for (int pl = 0; pl < 64; ++pl) {
    float v = tile[wv][lane][pl];
    float ln = gc * (v - mArr[pl]) * invArr[pl] + bc;
    unsigned short hb = f2h_bits(ln);
    ohb[(size_t)pl * C] = hb;
    olb[(size_t)pl * C] = f2h_bits((ln - h_bits2f(hb)) * 2048.f);
  }
}

// ------- MFMA GEMM: Y[b][o][n] = sum_c W[o][c] * Xt[b][n][c] -----------------
__global__ __launch_bounds__(256) void gemm_mfma_k(
    const float* __restrict__ W, const unsigned short* __restrict__ Xh,
    const unsigned short* __restrict__ Xl, float* __restrict__ Y,
    int O, int C, int N) {
  int t = threadIdx.x, lane = t & 63, wv = t >> 6;
  int lq = lane & 15, lg = lane >> 4;
  int n0 = blockIdx.x * 64, o0 = blockIdx.y * 64 + wv * 16;
  int b = blockIdx.z;
  const unsigned short* xbh = Xh + ((size_t)b * N + n0) * C;
  const unsigned short* xbl = Xl + ((size_t)b * N + n0) * C;
  const float* wr = W + (size_t)(o0 + lq) * C;
  fx4 ahi[4], alo[4];
  for (int nt = 0; nt < 4; ++nt) {
    ahi[nt] = (fx4){0.f, 0.f, 0.f, 0.f};
    alo[nt] = (fx4){0.f, 0.f, 0.f, 0.f};
  }
  for (int k0 = 0; k0 < C; k0 += 32) {
    float4 w0 = *(const float4*)(wr + k0 + lg * 8);
    float4 w1 = *(const float4*)(wr + k0 + lg * 8 + 4);
    float wv8[8] = {w0.x, w0.y, w0.z, w0.w, w1.x, w1.y, w1.z, w1.w};
    hfx8 ah, al;
#pragma unroll
    for (int i = 0; i < 8; ++i) {
      _Float16 h = (_Float16)wv8[i];
      ah[i] = h;
      al[i] = (_Float16)((wv8[i] - (float)h) * 2048.f);
    }
#pragma unroll
    for (int nt = 0; nt < 4; ++nt) {
      const unsigned short* bph = xbh + (size_t)(nt * 16 + lq) * C + k0 + lg * 8;
      const unsigned short* bpl = xbl + (size_t)(nt * 16 + lq) * C + k0 + lg * 8;
      hfx8 bh = *(const hfx8*)bph;
      hfx8 bl = *(const hfx8*)bpl;
      ahi[nt] = __builtin_amdgcn_mfma_f32_16x16x32_f16(ah, bh, ahi[nt], 0, 0, 0);
      alo[nt] = __builtin_amdgcn_mfma_f32_16x16x32_f16(al, bh, alo[nt], 0, 0, 0);
      alo[nt] = __builtin_amdgcn_mfma_f32_16x16x32_f16(ah, bl, alo[nt], 0, 0, 0);
    }
  }
  float* yb = Y + ((size_t)b * O + o0) * N + n0;
#pragma unroll
  for (int nt = 0; nt < 4; ++nt)
#pragma unroll
    for (int r = 0; r < 4; ++r)
      yb[(size_t)(lg * 4 + r) * N + nt * 16 + lq] = ahi[nt][r] + alo[nt][r] * (1.f / 2048.f);
}

// ---------------- fold heads: (b, ch, n) -> (bh, n, 64), optional L2 norm ----
__global__ void fold_k(const float* __restrict__ src, float* __restrict__ dst,
                       int bstride, int choff, int N, int donorm) {
  __shared__ float tile[64 * 65];
  __shared__ float part[4 * 64];
  __shared__ float invn[64];
  int t = threadIdx.x;
  int lane = t & 63, wv = t >> 6;
  int n0 = blockIdx.x * 64;
  int h = blockIdx.y, bi = blockIdx.z;
  const float* sb = src + (size_t)bi * bstride + (size_t)(choff + h * 64) * N + n0;
  for (int r = 0; r < 16; ++r) {
    int d = r * 4 + wv;
    tile[d * 65 + lane] = sb[(size_t)d * N + lane];
  }
  __syncthreads();
  if (donorm) {
    float s = 0.f;
    for (int r = 0; r < 16; ++r) {
      float v = tile[(wv + 4 * r) * 65 + lane];
      s += v * v;
    }
    part[wv * 64 + lane] = s;
    __syncthreads();
    if (t < 64) {
      float tot = part[t] + part[64 + t] + part[128 + t] + part[192 + t];
      invn[t] = 1.f / fmaxf(sqrtf(tot), 1e-12f);
    }
    __syncthreads();
  }
  float* db = dst + ((size_t)(bi * 8 + h) * N + n0) * 64;
  for (int r = 0; r < 16; ++r) {
    int nn = r * 4 + wv;
    float v = tile[lane * 65 + nn];
    if (donorm) v *= invn[nn];
    db[(size_t)nn * 64 + lane] = v;
  }
}

// ---------------- f32 -> split f16 (hi + lo*2048) ----------------------------
__global__ void tof2_k(const float* __restrict__ x, unsigned short* __restrict__ yh,
                       unsigned short* __restrict__ yl) {
  int i = blockIdx.x * 256 + threadIdx.x;
  float4 v = ((const float4*)x)[i];
  us4 h = {f2h_bits(v.x), f2h_bits(v.y), f2h_bits(v.z), f2h_bits(v.w)};
  us4 l = {f2h_bits((v.x - h_bits2f(h.x)) * 2048.f),
           f2h_bits((v.y - h_bits2f(h.y)) * 2048.f),
           f2h_bits((v.z - h_bits2f(h.z)) * 2048.f),
           f2h_bits((v.w - h_bits2f(h.w)) * 2048.f)};
  *(us4*)(yh + (size_t)i * 4) = h;
  *(us4*)(yl + (size_t)i * 4) = l;
}

// ---------------- centroid prep: csq (f32), -2c split f16 --------------------
__global__ void centprep_k(const float* __restrict__ cent, float* __restrict__ csq,
                           unsigned short* __restrict__ cb2h, unsigned short* __restrict__ cb2l) {
  int j = blockIdx.x, lane = threadIdx.x;  // blockDim = 64
  float c = cent[j * 64 + lane];
  float s = c * c;
  for (int off = 32; off; off >>= 1) s += __shfl_xor(s, off);
  if (lane == 0) csq[j] = s;
  float m2 = -2.f * c;
  unsigned short h = f2h_bits(m2);
  cb2h[j * 64 + lane] = h;
  cb2l[j * 64 + lane] = f2h_bits((m2 - h_bits2f(h)) * 2048.f);
}

// ---------------- MFMA nearest-centroid assign (f16 split, LDS-staged) -------
__global__ __launch_bounds__(256) void assign_mfma_k(
    const unsigned short* __restrict__ xh, const unsigned short* __restrict__ xl,
    const unsigned short* __restrict__ cb2h, const unsigned short* __restrict__ cb2l,
    const float* __restrict__ csq, int* __restrict__ aout) {
  __shared__ __align__(16) unsigned short clds[2][2][1024];  // [buf][hi/lo][16x64]
  int t = threadIdx.x, lane = t & 63, wv = t >> 6;
  int lq = lane & 15, lg = lane >> 4;
  int p0 = blockIdx.x * 64 + wv * 16;
  const unsigned short* xb = xh + (size_t)(p0 + lq) * 64;
  const unsigned short* xlb = xl + (size_t)(p0 + lq) * 64;
  hfx8 bh0 = *(const hfx8*)(xb + lg * 8);
  hfx8 bh1 = *(const hfx8*)(xb + 32 + lg * 8);
  hfx8 bl0 = *(const hfx8*)(xlb + lg * 8);
  hfx8 bl1 = *(const hfx8*)(xlb + 32 + lg * 8);

  int part = t >> 7;
  int abyte = (t & 127) * 16;
  int wbyte = abyte ^ (((abyte >> 7) & 7) << 4);
  const unsigned short* gsrc = (part ? cb2l : cb2h) + (abyte >> 1);
  int rowoff = lq * 128;
  int x0 = (lg * 16) ^ ((lq & 7) << 4);
  int x1 = (64 + lg * 16) ^ ((lq & 7) << 4);

  float best = 3.4e38f;
  int bestj = 0;

  uint4 r0 = *(const uint4*)(gsrc);
  *(uint4*)((char*)&clds[0][part][0] + wbyte) = r0;

  for (int s = 0; s < 64; ++s) {
    int cur = s & 1;
    __syncthreads();
    uint4 rn;
    if (s < 63) rn = *(const uint4*)(gsrc + (size_t)(s + 1) * 1024);
    __builtin_amdgcn_sched_barrier(0);
    const char* ph = (const char*)&clds[cur][0][0];
    const char* pl = (const char*)&clds[cur][1][0];
    hfx8 ah0 = *(const hfx8*)(ph + rowoff + x0);
    hfx8 ah1 = *(const hfx8*)(ph + rowoff + x1);
    hfx8 al0 = *(const hfx8*)(pl + rowoff + x0);
    hfx8 al1 = *(const hfx8*)(pl + rowoff + x1);
    fx4 chi = *(const fx4*)(csq + s * 16 + lg * 4);
    chi = __builtin_amdgcn_mfma_f32_16x16x32_f16(ah0, bh0, chi, 0, 0, 0);
    chi = __builtin_amdgcn_mfma_f32_16x16x32_f16(ah1, bh1, chi, 0, 0, 0);
    fx4 clo = (fx4){0.f, 0.f, 0.f, 0.f};
    clo = __builtin_amdgcn_mfma_f32_16x16x32_f16(ah0, bl0, clo, 0, 0, 0);
    clo = __builtin_amdgcn_mfma_f32_16x16x32_f16(ah1, bl1, clo, 0, 0, 0);
    clo = __builtin_amdgcn_mfma_f32_16x16x32_f16(al0, bh0, clo, 0, 0, 0);
    clo = __builtin_amdgcn_mfma_f32_16x16x32_f16(al1, bh1, clo, 0, 0, 0);
#pragma unroll
    for (int r_ = 0; r_ < 4; ++r_) {
      int j_ = s * 16 + lg * 4 + r_;
      float d2_ = chi[r_] + clo[r_] * (1.f / 2048.f);
      if (d2_ < best) { best = d2_; bestj = j_; }
    }
    __builtin_amdgcn_sched_barrier(0);
    if (s < 63) *(uint4*)((char*)&clds[cur ^ 1][part][0] + wbyte) = rn;
  }

  {
    float o = __shfl_xor(best, 16);
    int oj = __shfl_xor(bestj, 16);
    if (o < best || (o == best && oj < bestj)) { best = o; bestj = oj; }
    o = __shfl_xor(best, 32);
    oj = __shfl_xor(bestj, 32);
    if (o < best || (o == best && oj < bestj)) { best = o; bestj = oj; }
  }
  if (lg == 0) aout[p0 + lq] = bestj;
}

// ---------------- exact f32 L1 distance to assigned centroid -----------------
__global__ void dist_k(const float* __restrict__ x, const float* __restrict__ cent,
                       const int* __restrict__ asg, float* __restrict__ dout) {
  int t = threadIdx.x, lane = t & 63, wv = t >> 6;
  int p = blockIdx.x * 4 + wv;
  int a = asg[p];
  float v = fabsf(cent[(size_t)a * 64 + lane] - x[(size_t)p * 64 + lane]);
  for (int off = 32; off; off >>= 1) v += __shfl_xor(v, off);
  if (lane == 0) dout[p] = v;
}

// ---------------- segment sum via atomics ------------------------------------
__global__ void segsum_k(const float* __restrict__ x, const int* __restrict__ asg,
                         float* __restrict__ sums, float* __restrict__ cnt) {
  int t = threadIdx.x, lane = t & 63, wv = t >> 6;
  int p = blockIdx.x * 4 + wv;
  int a = asg[p];
  float v = x[(size_t)p * 64 + lane];
  atomicAdd(&sums[a * 64 + lane], v);
  if (lane == 0) atomicAdd(&cnt[a], 1.0f);
}

// ---------------- centroid update --------------------------------------------
__global__ void centup_k(float* __restrict__ cent, const float* __restrict__ sums,
                         const float* __restrict__ cnt) {
  int i = blockIdx.x * 256 + threadIdx.x;  // 65536 total
  int j = i >> 6;
  float c = cnt[j];
  if (c > 0.f) cent[i] = sums[i] / fmaxf(c, 1.f);
}

// ---------------- per-bh top-1024 by descending dist (stable ties) -----------
__global__ void topk_k(const float* __restrict__ dist, int* __restrict__ sel) {
  __shared__ unsigned long long keys[2048];
  int bh = blockIdx.x, t = threadIdx.x;
  for (int i = t; i < 2048; i += 256) {
    float d = dist[bh * 2048 + i];
    unsigned int db = __float_as_uint(d);  // d >= 0 -> monotonic
    keys[i] = ((unsigned long long)db << 32) | (unsigned int)(2047 - i);
  }
  __syncthreads();
  for (int k = 2; k <= 2048; k <<= 1) {
    for (int j = k >> 1; j > 0; j >>= 1) {
      for (int i = t; i < 2048; i += 256) {
        int ixj = i ^ j;
        if (ixj > i) {
          unsigned long long a = keys[i], b = keys[ixj];
          bool up = ((i & k) == 0);
          bool sw = up ? (a < b) : (a > b);  // descending overall
          if (sw) { keys[i] = b; keys[ixj] = a; }
        }
      }
      __syncthreads();
    }
  }
  for (int i = t; i < 1024; i += 256) {
    sel[bh * 1024 + i] = 2047 - (int)(keys[i] & 0xffffffffu);
  }
}

// ---------------- gather selected rows -> kh (bf16 row-major), vT (bf16 d-major)
__global__ void gatherb_k(const float* __restrict__ kbuf, const float* __restrict__ vbuf,
                          const int* __restrict__ sel, unsigned short* __restrict__ kh,
                          unsigned short* __restrict__ vT) {
  __shared__ unsigned short tile[64][66];
  int t = threadIdx.x, lane = t & 63, wv = t >> 6;
  int bh = blockIdx.y, i0 = blockIdx.x * 64;
  for (int r = 0; r < 16; ++r) {
    int i = r * 4 + wv;
    int src = sel[bh * 1024 + i0 + i];
    float kvv = kbuf[((size_t)bh * 2048 + src) * 64 + lane];
    kh[((size_t)bh * 1024 + i0 + i) * 64 + lane] = f2bf(kvv);
    float vv = vbuf[((size_t)bh * 2048 + src) * 64 + lane];
    tile[i][lane] = f2bf(vv);
  }
  __syncthreads();
  for (int r = 0; r < 16; ++r) {
    int d = r * 4 + wv;
    vT[((size_t)bh * 64 + d) * 1024 + i0 + lane] = tile[lane][d];
  }
}

// ---------------- f32 -> bf16 bulk convert -----------------------------------
__global__ void tobf_k(const float* __restrict__ x, unsigned short* __restrict__ y) {
  int i = blockIdx.x * 256 + threadIdx.x;
  float4 v = ((const float4*)x)[i];
  us4 o = {f2bf(v.x), f2bf(v.y), f2bf(v.z), f2bf(v.w)};
  *(us4*)(y + (size_t)i * 4) = o;
}

// ---------------- MFMA flash attention (K/V LDS-staged, barrier-light) -------
// P handoff buffer is per-wave -> no cross-wave barrier needed for it; the only
// __syncthreads per tile is the K/V double-buffer staging barrier.
__global__ __launch_bounds__(256) void attn_mfma_k(
    const unsigned short* __restrict__ qh, const unsigned short* __restrict__ kh,
    const unsigned short* __restrict__ vT,
    unsigned short* __restrict__ oh, unsigned short* __restrict__ ol) {
  __shared__ __align__(16) unsigned short kvlds[2][2][4096];  // [buf][K/V][64x64]
  __shared__ unsigned short plds[4][16][72];
  int t = threadIdx.x, lane = t & 63, wv = t >> 6;
  int lq = lane & 15, lg = lane >> 4;
  int bh = blockIdx.y;
  int q0 = blockIdx.x * 64 + wv * 16;
  const unsigned short* qbase = qh + ((size_t)bh * 4096 + q0 + lq) * 64;
  bfx8 qf0 = *(const bfx8*)(qbase + lg * 8);
  bfx8 qf1 = *(const bfx8*)(qbase + 32 + lg * 8);
  fx4 acc[4];
  for (int nt = 0; nt < 4; ++nt) acc[nt] = (fx4){0.f, 0.f, 0.f, 0.f};
  float lsum = 0.f;
  const unsigned short* kbase = kh + (size_t)bh * 1024 * 64;
  const unsigned short* vbase = vT + (size_t)bh * 64 * 1024;

  // staging: thread stages 32B of K and 32B of V per tile
  int srow = t >> 2;
  int scolb = (t & 3) * 32;
  const char* gK = (const char*)kbase + (size_t)srow * 128 + scolb;   // + s*8192
  const char* gV = (const char*)vbase + (size_t)srow * 2048 + scolb;  // + s*128
  int sw_w = (srow & 7) << 4;
  int wb0 = srow * 128 + (scolb ^ sw_w);
  int wb1 = srow * 128 + ((scolb + 16) ^ sw_w);

  {
    uint4 k0 = *(const uint4*)(gK);
    uint4 k1 = *(const uint4*)(gK + 16);
    uint4 v0 = *(const uint4*)(gV);
    uint4 v1 = *(const uint4*)(gV + 16);
    *(uint4*)((char*)&kvlds[0][0][0] + wb0) = k0;
    *(uint4*)((char*)&kvlds[0][0][0] + wb1) = k1;
    *(uint4*)((char*)&kvlds[0][1][0] + wb0) = v0;
    *(uint4*)((char*)&kvlds[0][1][0] + wb1) = v1;
  }

  int swr = (lq & 7) << 4;  // read-side swizzle (row & 7 == lq & 7)
  int rc0 = (lg * 16) ^ swr;
  int rc1 = (64 + lg * 16) ^ swr;

  for (int s = 0; s < 16; ++s) {
    int cur = s & 1;
    __syncthreads();
    uint4 nk0, nk1, nv0, nv1;
    if (s < 15) {
      const char* gKn = gK + (size_t)(s + 1) * 8192;
      const char* gVn = gV + (size_t)(s + 1) * 128;
      nk0 = *(const uint4*)(gKn);
      nk1 = *(const uint4*)(gKn + 16);
      nv0 = *(const uint4*)(gVn);
      nv1 = *(const uint4*)(gVn + 16);
    }
    __builtin_amdgcn_sched_barrier(0);
    const char* Kb = (const char*)&kvlds[cur][0][0];
    const char* Vb = (const char*)&kvlds[cur][1][0];
    fx4 sS[4];
#pragma unroll
    for (int mt = 0; mt < 4; ++mt) {
      int rowb = (mt * 16 + lq) * 128;
      bfx8 a0 = *(const bfx8*)(Kb + rowb + rc0);
      bfx8 a1 = *(const bfx8*)(Kb + rowb + rc1);
      fx4 c = (fx4){0.f, 0.f, 0.f, 0.f};
      c = __builtin_amdgcn_mfma_f32_16x16x32_bf16(a0, qf0, c, 0, 0, 0);
      c = __builtin_amdgcn_mfma_f32_16x16x32_bf16(a1, qf1, c, 0, 0, 0);
      sS[mt] = c;
    }
#pragma unroll
    for (int mt = 0; mt < 4; ++mt) {
      float p0 = __expf(sS[mt].x), p1 = __expf(sS[mt].y);
      float p2 = __expf(sS[mt].z), p3 = __expf(sS[mt].w);
      lsum += (p0 + p1) + (p2 + p3);
      us4 pk = {f2bf(p0), f2bf(p1), f2bf(p2), f2bf(p3)};
      *(us4*)&plds[wv][lq][mt * 16 + lg * 4] = pk;
    }
    bfx8 pa0 = *(const bfx8*)&plds[wv][lq][lg * 8];
    bfx8 pa1 = *(const bfx8*)&plds[wv][lq][32 + lg * 8];
#pragma unroll
    for (int nt = 0; nt < 4; ++nt) {
      int rowb = (nt * 16 + lq) * 128;
      bfx8 b0 = *(const bfx8*)(Vb + rowb + rc0);
      bfx8 b1 = *(const bfx8*)(Vb + rowb + rc1);
      acc[nt] = __builtin_amdgcn_mfma_f32_16x16x32_bf16(pa0, b0, acc[nt], 0, 0, 0);
      acc[nt] = __builtin_amdgcn_mfma_f32_16x16x32_bf16(pa1, b1, acc[nt], 0, 0, 0);
    }
    __builtin_amdgcn_sched_barrier(0);
    if (s < 15) {
      char* dK = (char*)&kvlds[cur ^ 1][0][0];
      char* dV = (char*)&kvlds[cur ^ 1][1][0];
      *(uint4*)(dK + wb0) = nk0;
      *(uint4*)(dK + wb1) = nk1;
      *(uint4*)(dV + wb0) = nv0;
      *(uint4*)(dV + wb1) = nv1;
    }
  }
  lsum += __shfl_xor(lsum, 16);
  lsum += __shfl_xor(lsum, 32);
  int bi = bh >> 3, hd = bh & 7;
  for (int r = 0; r < 4; ++r) {
    float inv = 1.f / __shfl(lsum, lg * 4 + r);
    size_t rowb = ((size_t)bi * 4096 + q0 + lg * 4 + r) * 512 + hd * 64;
    for (int nt = 0; nt < 4; ++nt) {
      float val = acc[nt][r] * inv;
      unsigned short hb = f2h_bits(val);
      oh[rowb + nt * 16 + lq] = hb;
      ol[rowb + nt * 16 + lq] = f2h_bits((val - h_bits2f(hb)) * 2048.f);
    }
  }
}

// ---------------- final LN + gamma*ln + residual (wave-split channels) -------
__global__ __launch_bounds__(256) void final_k(
    const float* __restrict__ y, const float* __restrict__ g,
    const float* __restrict__ bta, const float* __restrict__ gamma,
    const float* __restrict__ qs, float* __restrict__ out) {
  __shared__ float p1[4][64], p2[4][64];
  __shared__ float mArr[64], invArr[64];
  int t = threadIdx.x, lane = t & 63, wv = t >> 6;
  int n0 = blockIdx.x * 64, bi = blockIdx.y;
  const float* yb = y + (size_t)bi * CDIM * NQ + n0 + lane;
  float s = 0.f, s2 = 0.f;
  for (int cl = 0; cl < 64; ++cl) {
    float v = yb[(size_t)(wv * 64 + cl) * NQ];
    s += v;
    s2 += v * v;
  }
  p1[wv][lane] = s;
  p2[wv][lane] = s2;
  __syncthreads();
  if (t < 64) {
    float ts = p1[0][t] + p1[1][t] + p1[2][t] + p1[3][t];
    float ts2 = p2[0][t] + p2[1][t] + p2[2][t] + p2[3][t];
    float m = ts / CDIM;
    float var = ts2 / CDIM - m * m;
    mArr[t] = m;
    invArr[t] = 1.f / (sqrtf(fmaxf(var, 0.f)) + 1e-6f);
  }
  __syncthreads();
  float gm = gamma[0];
  float m = mArr[lane], inv = invArr[lane];
  const float* qb = qs + (size_t)bi * CDIM * NQ + n0 + lane;
  float* ob = out + (size_t)bi * CDIM * NQ + n0 + lane;
  for (int cl = 0; cl < 64; ++cl) {
    int c = wv * 64 + cl;
    float v = yb[(size_t)c * NQ];
    float ln = g[c] * (v - m) * inv + bta[c];
    ob[(size_t)c * NQ] = gm * ln + qb[(size_t)c * NQ];
  }
}

extern "C" void kernel_launch(void* const* d_in, const int* in_sizes, int n_in,
                              void* d_out, int out_size, void* d_ws, size_t ws_size,
                              hipStream_t stream) {
  const float* qsrc = (const float*)d_in[0];
  const float* ctx = (const float*)d_in[1];
  const float* w_q = (const float*)d_in[2];
  const float* w_kv = (const float*)d_in[3];
  const float* w_out = (const float*)d_in[4];
  const float* cn_g = (const float*)d_in[5];
  const float* cn_b = (const float*)d_in[6];
  const float* qn_g = (const float*)d_in[7];
  const float* qn_b = (const float*)d_in[8];
  const float* on_g = (const float*)d_in[9];
  const float* on_b = (const float*)d_in[10];
  const float* gamma = (const float*)d_in[11];

  // scratch layout (floats); total 22,267,904 floats = 89.1 MB
  if (ws_size < (size_t)22267904 * 4) return;
  float* ws = (float*)d_ws;
  float* r_ctx = ws;                      // 1,048,576 f: ctx split-f16; later kh/vT
  float* r_kv = r_ctx + 1048576;          // 4,194,304 f: kv f32; later kbh/kbl; later attnt split
  float* r_qs = r_kv + 4194304;           // 2,097,152 f: qs split-f16; later cb2h/l, ybuf
  float* r_q3 = r_qs + 2097152;           // 4,194,304 f: q3 f32; later qbh/qbl
  float* qbuf = r_q3 + 4194304;           // 4,194,304 f
  float* kbuf = qbuf + 4194304;           // 2,097,152 f
  float* vbuf = kbuf + 2097152;           // 2,097,152 f
  float* cent = vbuf + 2097152;           // 65,536 f
  float* csq = cent + 65536;              // 1,024 f
  float* sums = csq + 1024;               // 65,536 f
  float* cnt = sums + 65536;              // 1,024 f
  int* asg = (int*)(cnt + 1024);          // 65,536 i
  float* dist = (float*)(asg + 65536);    // 32,768 f
  int* sel = (int*)(dist + 32768);        // 16,384 i
  float* kgreg = (float*)(sel + 16384);   // 2,097,152 f (qh bf16)

  unsigned short* ctxth = (unsigned short*)r_ctx;   // [b][2048][256] f16 hi
  unsigned short* ctxtl = ctxth + (size_t)BB * NK * CDIM;  // lo
  unsigned short* qsth = (unsigned short*)r_qs;     // [b][4096][256] f16 hi
  unsigned short* qstl = qsth + (size_t)BB * NQ * CDIM;    // lo
  float* kvf = r_kv;                      // [b][1024][2048] f32
  float* q3f = r_q3;                      // [b][512][4096] f32
  unsigned short* qh = (unsigned short*)kgreg;      // 4M bf16
  unsigned short* kh = (unsigned short*)r_ctx;      // 1M bf16 (ctx split dead)
  unsigned short* vT = kh + 1048576;                // 1M bf16
  unsigned short* qbh = (unsigned short*)r_q3;      // 4M f16 (q split hi)
  unsigned short* qbl = qbh + (size_t)NPQ * 64;     // 4M f16 (lo)
  unsigned short* kbh = (unsigned short*)r_kv;      // 2M f16 (k split hi)
  unsigned short* kbl = kbh + (size_t)NPK * 64;     // 2M f16 (lo)
  unsigned short* cb2h = (unsigned short*)r_qs;     // 64K f16 (-2c hi)
  unsigned short* cb2l = cb2h + 65536;              // 64K f16 (lo)
  unsigned short* attnth = (unsigned short*)r_kv;   // [b][4096][512] f16 hi (kb split dead)
  unsigned short* attntl = attnth + (size_t)BB * NQ * 512;  // lo
  float* ybuf = r_qs;                     // [b][256][4096] f32 (cb2 dead)

  // 1. channel LayerNorms -> transposed split-f16
  chan_ln_tsplit_k<<<dim3(NK / 64, BB), 256, 0, stream>>>(ctx, cn_g, cn_b, ctxth, ctxtl, CDIM, NK);
  chan_ln_tsplit_k<<<dim3(NQ / 64, BB), 256, 0, stream>>>(qsrc, qn_g, qn_b, qsth, qstl, CDIM, NQ);
  // 2. MFMA projections
  gemm_mfma_k<<<dim3(NK / 64, 1024 / 64, BB), 256, 0, stream>>>(w_kv, ctxth, ctxtl, kvf, 1024, CDIM, NK);
  gemm_mfma_k<<<dim3(NQ / 64, 512 / 64, BB), 256, 0, stream>>>(w_q, qsth, qstl, q3f, 512, CDIM, NQ);
  // 3. fold heads (+L2-normalize q,k)
  fold_k<<<dim3(NQ / 64, 8, BB), 256, 0, stream>>>(q3f, qbuf, 512 * NQ, 0, NQ, 1);
  fold_k<<<dim3(NK / 64, 8, BB), 256, 0, stream>>>(kvf, kbuf, 1024 * NK, 0, NK, 1);
  fold_k<<<dim3(NK / 64, 8, BB), 256, 0, stream>>>(kvf, vbuf, 1024 * NK, 512, NK, 0);
  // 4. split-f16 conversions (q3/kv f32 regions now reusable)
  tof2_k<<<NPQ * 64 / 1024, 256, 0, stream>>>(qbuf, qbh, qbl);
  tof2_k<<<NPK * 64 / 1024, 256, 0, stream>>>(kbuf, kbh, kbl);
  // 5. k-means (init = first 1024 q rows)
  hipMemcpyAsync(cent, qbuf, 65536 * sizeof(float), hipMemcpyDeviceToDevice, stream);
  for (int it = 0; it < 4; ++it) {
    centprep_k<<<1024, 64, 0, stream>>>(cent, csq, cb2h, cb2l);
    hipMemsetAsync(sums, 0, (65536 + 1024) * sizeof(float), stream);
    assign_mfma_k<<<NPQ / 64, 256, 0, stream>>>(qbh, qbl, cb2h, cb2l, csq, asg);
    segsum_k<<<NPQ / 4, 256, 0, stream>>>(qbuf, asg, sums, cnt);
    centup_k<<<65536 / 256, 256, 0, stream>>>(cent, sums, cnt);
  }
  // 6. score keys: argmin (MFMA) -> exact f32 L1 dist -> per-head top-1024
  centprep_k<<<1024, 64, 0, stream>>>(cent, csq, cb2h, cb2l);
  assign_mfma_k<<<NPK / 64, 256, 0, stream>>>(kbh, kbl, cb2h, cb2l, csq, asg);
  dist_k<<<NPK / 4, 256, 0, stream>>>(kbuf, cent, asg, dist);
  topk_k<<<BH, 256, 0, stream>>>(dist, sel);
  // 7. bf16 conversions + gather (kh row-major, vT transposed)
  tobf_k<<<NPQ * 64 / 1024, 256, 0, stream>>>(qbuf, qh);
  gatherb_k<<<dim3(TOPK / 64, BH), 256, 0, stream>>>(kbuf, vbuf, sel, kh, vT);
  // 8. MFMA attention -> split-f16 un-folded [b][n][512]
  attn_mfma_k<<<dim3(NQ / 64, BH), 256, 0, stream>>>(qh, kh, vT, attnth, attntl);
  // 9. output projection (MFMA)
  gemm_mfma_k<<<dim3(NQ / 64, 256 / 64, BB), 256, 0, stream>>>(w_out, attnth, attntl, ybuf, 256, 512, NQ);
  // 10. final LN + residual
  final_k<<<dim3(NQ / 64, BB), 256, 0, stream>>>(ybuf, on_g, on_b, gamma, qsrc, (float*)d_out);
}